// Round 12
// baseline (381.889 us; speedup 1.0000x reference)
//
#include <hip/hip_runtime.h>
#include <math.h>

#define NB 4
#define N 2000
#define DIN 128
#define DH 256
#define NROWS (NB*N)          // 8000
#define EPSF 1e-8f

typedef __attribute__((ext_vector_type(8))) short bf16x8;
typedef __attribute__((ext_vector_type(4))) float f32x4;

// ---------------- helpers ----------------

__device__ __forceinline__ float gelu_t(float x){
    // jax.nn.gelu approximate=True (tanh form)
    float z = 0.7978845608028654f * fmaf(0.044715f * x * x, x, x);
    z = fminf(fmaxf(z, -20.f), 20.f);
    float e = __expf(2.f * z);
    return 0.5f * x * (1.f + (e - 1.f) / (e + 1.f));
}

__device__ __forceinline__ unsigned short f2bf(float f){   // RNE f32->bf16 bits
    unsigned u = __float_as_uint(f);
    return (unsigned short)((u + 0x7FFFu + ((u >> 16) & 1u)) >> 16);
}

// full descending bitonic sort of 64 values across a wave (lane 0 = largest)
__device__ __forceinline__ float wave_sort64_desc(float v){
    const int lane = threadIdx.x & 63;
    #pragma unroll
    for (int k = 2; k <= 64; k <<= 1){
        #pragma unroll
        for (int j = k >> 1; j >= 1; j >>= 1){
            float o = __shfl_xor(v, j, 64);
            bool keepMax = ((lane & k) == 0) == ((lane & j) == 0);
            v = keepMax ? fmaxf(v, o) : fminf(v, o);
        }
    }
    return v;
}

// descending bitonic sort of 128 values (2 regs/lane; element idx = 2*lane+r)
__device__ __forceinline__ void sort128_desc(float &v0, float &v1){
    const int lane = threadIdx.x & 63;
    #pragma unroll
    for (int k = 2; k <= 128; k <<= 1){
        #pragma unroll
        for (int j = k >> 1; j >= 2; j >>= 1){
            int lj = j >> 1;
            float o0 = __shfl_xor(v0, lj, 64);
            float o1 = __shfl_xor(v1, lj, 64);
            int idx0 = 2*lane, idx1 = 2*lane + 1;
            bool km0 = ((idx0 & k) == 0) == ((idx0 & j) == 0);
            bool km1 = ((idx1 & k) == 0) == ((idx1 & j) == 0);
            v0 = km0 ? fmaxf(v0, o0) : fminf(v0, o0);
            v1 = km1 ? fmaxf(v1, o1) : fminf(v1, o1);
        }
        {   // j == 1: within-lane CAS
            bool up = (((2*lane) & k) == 0);
            float a = fmaxf(v0, v1), b = fminf(v0, v1);
            v0 = up ? a : b;
            v1 = up ? b : a;
        }
    }
}

// Non-destructive wave-local exact 20th-largest (with multiplicity) fallback:
// descending distinct-value extraction; <=20 iterations; register-only.
__device__ __forceinline__ float wave_topk20_slow32(const float (&v)[32]){
    float cur = 1e30f, kth = 0.f;
    int consumed = 0;
    for (int it = 0; it < 20; ++it){
        if (consumed >= 20) break;
        float bm = -3.f;
        #pragma unroll
        for (int i = 0; i < 32; ++i){ if (v[i] < cur) bm = fmaxf(bm, v[i]); }
        #pragma unroll
        for (int mm = 1; mm < 64; mm <<= 1) bm = fmaxf(bm, __shfl_xor(bm, mm, 64));
        int c = 0;
        #pragma unroll
        for (int i = 0; i < 32; ++i) c += (v[i] == bm) ? 1 : 0;
        #pragma unroll
        for (int mm = 1; mm < 64; mm <<= 1) c += __shfl_xor(c, mm, 64);
        consumed += c;
        kth = bm;
        cur = bm;
    }
    return kth;
}

// Exact wave-local 20th-largest (with multiplicity) of 64 lanes x 32 regs.
// cl: this wave's private 128-float LDS region. MUST be called by ALL
// threads of the block at the same program point: the two __syncthreads()
// are uniform (outside any divergent branch). Three paths by candidate
// count (wave-uniform choice, no barriers inside): <=64 -> 21-stage sort64
// (expected case, E[total]~22), <=128 -> sort128, else register fallback.
__device__ __forceinline__ float wave_topk20_sync(const float (&v)[32], float* cl){
    const int lane = threadIdx.x & 63;
    float mx = v[0];
    #pragma unroll
    for (int i = 1; i < 32; ++i) mx = fmaxf(mx, v[i]);
    float sm = wave_sort64_desc(mx);
    float u = __shfl(sm, 19, 64);       // 20th-largest lane-max: u <= true kth
    int cnt = 0;
    #pragma unroll
    for (int i = 0; i < 32; ++i) cnt += (v[i] >= u) ? 1 : 0;
    int incl = cnt;
    #pragma unroll
    for (int s = 1; s < 64; s <<= 1){
        int o = __shfl_up(incl, s, 64);
        if (lane >= s) incl += o;
    }
    const int total = __shfl(incl, 63, 64);   // >= 20 by construction of u
    const bool fast = (total <= 128);   // wave-uniform
    if (fast){
        int offs = incl - cnt;
        #pragma unroll
        for (int i = 0; i < 32; ++i){
            if (v[i] >= u) cl[offs++] = v[i];
        }
    }
    __syncthreads();                    // uniform: fences candidate writes
    float kth;
    if (total <= 64){                   // short path: single-reg bitonic sort
        float c0 = (lane < total) ? cl[lane] : -3.f;
        c0 = wave_sort64_desc(c0);
        kth = __shfl(c0, 19, 64);       // element index 19
    } else if (fast){
        float c0 = (2*lane     < total) ? cl[2*lane]     : -3.f;
        float c1 = (2*lane + 1 < total) ? cl[2*lane + 1] : -3.f;
        sort128_desc(c0, c1);
        kth = __shfl(c1, 9, 64);        // element index 19
    } else {
        kth = wave_topk20_slow32(v);
    }
    __syncthreads();                    // uniform: cl safe to reuse after return
    return kth;
}

// Per-wave MFMA GEMM: out16x64 = A(16x256, bf16 LDS) @ Wt-slice.
// Wt is [col][k] bf16. Wave covers cols cbase..cbase+63 as 4 16-col tiles.
// Internal barrier after A-frag loads => caller may overwrite sA after return.
__device__ __forceinline__ void mfma_gemm16(
    const unsigned short (*__restrict__ sA)[264], const unsigned short* __restrict__ Wt,
    int l15, int hi, int cbase, f32x4 acc[4])
{
    bf16x8 a[8];
    #pragma unroll
    for (int kb = 0; kb < 8; ++kb)
        a[kb] = *(const bf16x8*)&sA[l15][kb*32 + hi*8];
    __syncthreads();                     // all waves' A-frags in regs
    const unsigned short* wp0 = Wt + (size_t)(cbase      + l15)*256 + hi*8;
    const unsigned short* wp1 = Wt + (size_t)(cbase + 16 + l15)*256 + hi*8;
    const unsigned short* wp2 = Wt + (size_t)(cbase + 32 + l15)*256 + hi*8;
    const unsigned short* wp3 = Wt + (size_t)(cbase + 48 + l15)*256 + hi*8;
    #pragma unroll
    for (int kb = 0; kb < 8; ++kb){
        bf16x8 b0 = *(const bf16x8*)(wp0 + kb*32);
        bf16x8 b1 = *(const bf16x8*)(wp1 + kb*32);
        bf16x8 b2 = *(const bf16x8*)(wp2 + kb*32);
        bf16x8 b3 = *(const bf16x8*)(wp3 + kb*32);
        acc[0] = __builtin_amdgcn_mfma_f32_16x16x32_bf16(a[kb], b0, acc[0], 0, 0, 0);
        acc[1] = __builtin_amdgcn_mfma_f32_16x16x32_bf16(a[kb], b1, acc[1], 0, 0, 0);
        acc[2] = __builtin_amdgcn_mfma_f32_16x16x32_bf16(a[kb], b2, acc[2], 0, 0, 0);
        acc[3] = __builtin_amdgcn_mfma_f32_16x16x32_bf16(a[kb], b3, acc[3], 0, 0, 0);
    }
}

// ---------------- kernels ----------------

// Weight prep: Wt[m][c][k] = bf16(W[m][k][c]), 6 matrices 256x256. Grid (8,8,6).
__global__ __launch_bounds__(256) void k_wcvt(
    const float* __restrict__ w10, const float* __restrict__ w20,
    const float* __restrict__ w11, const float* __restrict__ w21,
    const float* __restrict__ gw1, const float* __restrict__ gw2,
    unsigned short* __restrict__ Wt)
{
    __shared__ float t[32][33];
    const int m = blockIdx.z;
    const float* W = (m==0)?w10:(m==1)?w20:(m==2)?w11:(m==3)?w21:(m==4)?gw1:gw2;
    unsigned short* out = Wt + (size_t)m*65536;
    const int k0 = blockIdx.y*32, c0 = blockIdx.x*32;
    const int tx = threadIdx.x & 31, ty = threadIdx.x >> 5;
    #pragma unroll
    for (int j = 0; j < 4; ++j){
        int k = ty*4 + j;
        t[k][tx] = W[(size_t)(k0+k)*256 + c0+tx];
    }
    __syncthreads();
    #pragma unroll
    for (int j = 0; j < 4; ++j){
        int c = ty*4 + j;
        out[(size_t)(c0+c)*256 + k0+tx] = f2bf(t[tx][c]);
    }
}

// Encoder bottleneck + projection + FDG embedding. 8 rows/block, 1000 blocks.
__global__ __launch_bounds__(256) void k_enc(
    const float* __restrict__ X,
    const float* __restrict__ lg, const float* __restrict__ lb,
    const float* __restrict__ w1, const float* __restrict__ b1,
    const float* __restrict__ w2, const float* __restrict__ b2,
    const float* __restrict__ pw, const float* __restrict__ pb,
    const float* __restrict__ fB,
    float* __restrict__ hid, float* __restrict__ Zn)
{
    __shared__ float sH[8][132];
    __shared__ float sT[8][68];
    __shared__ float sXm[8][132];
    const int tid = threadIdx.x;
    const int lane = tid & 63;
    const int wave = tid >> 6;
    const int rg = wave * 2;
    const int row0 = blockIdx.x * 8;
    const int cx = lane * 2;
    float2 x0 = *(const float2*)(X + (size_t)(row0+rg  )*128 + cx);
    float2 x1 = *(const float2*)(X + (size_t)(row0+rg+1)*128 + cx);
    {   // LN over 128 (two rows per wave, full-wave reduce)
        float sa = x0.x + x0.y, sb = x1.x + x1.y;
        float qa = x0.x*x0.x + x0.y*x0.y, qb = x1.x*x1.x + x1.y*x1.y;
        #pragma unroll
        for (int m = 1; m < 64; m <<= 1){
            sa += __shfl_xor(sa, m, 64); sb += __shfl_xor(sb, m, 64);
            qa += __shfl_xor(qa, m, 64); qb += __shfl_xor(qb, m, 64);
        }
        float mua = sa*(1.f/128.f), mub = sb*(1.f/128.f);
        float rsa = rsqrtf(qa*(1.f/128.f) - mua*mua + 1e-5f);
        float rsb = rsqrtf(qb*(1.f/128.f) - mub*mub + 1e-5f);
        float2 gg = *(const float2*)(lg + cx);
        float2 bb = *(const float2*)(lb + cx);
        sH[rg  ][cx] = (x0.x - mua)*rsa*gg.x + bb.x;
        sH[rg  ][cx+1] = (x0.y - mua)*rsa*gg.y + bb.y;
        sH[rg+1][cx] = (x1.x - mub)*rsb*gg.x + bb.x;
        sH[rg+1][cx+1] = (x1.y - mub)*rsb*gg.y + bb.y;
    }
    __syncthreads();
    {   // GEMM1 (128->64): one col per lane, two rows
        float a0 = 0.f, a1 = 0.f;
        #pragma unroll 4
        for (int k = 0; k < 128; ++k){
            float h0 = sH[rg][k], h1 = sH[rg+1][k];
            float wk = w1[k*64 + lane];
            a0 = fmaf(h0, wk, a0);
            a1 = fmaf(h1, wk, a1);
        }
        float bb = b1[lane];
        sT[rg  ][lane] = gelu_t(a0 + bb);
        sT[rg+1][lane] = gelu_t(a1 + bb);
    }
    __syncthreads();
    {   // GEMM2 (64->128): Xm = X + t@w2 + b2 -> sXm
        float p0x=0.f,p0y=0.f,p1x=0.f,p1y=0.f;
        #pragma unroll 4
        for (int k = 0; k < 64; ++k){
            float t0 = sT[rg][k], t1 = sT[rg+1][k];
            float2 w = *(const float2*)(w2 + k*128 + cx);
            p0x = fmaf(t0, w.x, p0x); p0y = fmaf(t0, w.y, p0y);
            p1x = fmaf(t1, w.x, p1x); p1y = fmaf(t1, w.y, p1y);
        }
        float2 bb = *(const float2*)(b2 + cx);
        sXm[rg  ][cx]   = x0.x + p0x + bb.x;
        sXm[rg  ][cx+1] = x0.y + p0y + bb.y;
        sXm[rg+1][cx]   = x1.x + p1x + bb.x;
        sXm[rg+1][cx+1] = x1.y + p1y + bb.y;
    }
    __syncthreads();
    {   // GEMM3: hid = Xm @ proj_w + proj_b, col-split per wave (64 cols each)
        const int ri = lane >> 4;
        const int wc = wave*64 + (lane & 15)*4;
        float a0[4] = {0,0,0,0}, a1[4] = {0,0,0,0};
        #pragma unroll 4
        for (int k = 0; k < 128; ++k){
            float h0 = sXm[ri*2][k], h1 = sXm[ri*2+1][k];
            float4 w = *(const float4*)(pw + k*256 + wc);
            a0[0]=fmaf(h0,w.x,a0[0]); a0[1]=fmaf(h0,w.y,a0[1]); a0[2]=fmaf(h0,w.z,a0[2]); a0[3]=fmaf(h0,w.w,a0[3]);
            a1[0]=fmaf(h1,w.x,a1[0]); a1[1]=fmaf(h1,w.y,a1[1]); a1[2]=fmaf(h1,w.z,a1[2]); a1[3]=fmaf(h1,w.w,a1[3]);
        }
        float4 bb = *(const float4*)(pb + wc);
        float4 o0 = make_float4(a0[0]+bb.x, a0[1]+bb.y, a0[2]+bb.z, a0[3]+bb.w);
        float4 o1 = make_float4(a1[0]+bb.x, a1[1]+bb.y, a1[2]+bb.z, a1[3]+bb.w);
        *(float4*)(hid + (size_t)(row0+ri*2  )*256 + wc) = o0;
        *(float4*)(hid + (size_t)(row0+ri*2+1)*256 + wc) = o1;
    }
    if (tid < 128){   // Z = Xm @ fdg_B^T ; Zn = Z/(||Z||+eps)
        const int r = tid >> 4, q = tid & 15;
        float z = 0.f;
        #pragma unroll 4
        for (int k = 0; k < 128; ++k) z = fmaf(sXm[r][k], fB[q*128 + k], z);
        float s2 = z*z;
        #pragma unroll
        for (int m = 1; m < 16; m <<= 1) s2 += __shfl_xor(s2, m, 64);
        Zn[(size_t)(row0 + r)*16 + q] = z / (sqrtf(s2) + EPSF);
    }
}

// history -> normalized (pre-scaled by 1/8), stored TRANSPOSED: HnT[b][t][n]
__global__ __launch_bounds__(256) void k_hist(const float* __restrict__ H, float* __restrict__ HnT)
{
    const int row  = blockIdx.x * 4 + (threadIdx.x >> 6);
    const int lane = threadIdx.x & 63;
    float v = H[(size_t)row*64 + lane];
    float s = v;
    #pragma unroll
    for (int mm = 1; mm < 64; mm <<= 1) s += __shfl_xor(s, mm, 64);
    float mu = s * (1.f/64.f);
    float d = v - mu;
    float s2 = d*d;
    #pragma unroll
    for (int mm = 1; mm < 64; mm <<= 1) s2 += __shfl_xor(s2, mm, 64);
    float sd = sqrtf(s2 * (1.f/64.f));
    const int b = row / N, nloc = row % N;
    HnT[(size_t)b*64*N + (size_t)lane*N + nloc] = d / ((sd + EPSF) * 8.f);
}

// Fused residual MLP blocks 0+1 + gblk-LN (hh). MFMA bf16. 16 rows/block.
__global__ __launch_bounds__(256) void k_mlp2(
    float* __restrict__ hid, const unsigned short* __restrict__ Wtb,
    const float* __restrict__ g0, const float* __restrict__ be0,
    const float* __restrict__ b10, const float* __restrict__ b20,
    const float* __restrict__ g1, const float* __restrict__ be1,
    const float* __restrict__ b11, const float* __restrict__ b21,
    const float* __restrict__ hg, const float* __restrict__ hb,
    float* __restrict__ hh_out)
{
    __shared__ float sR[16][264];
    __shared__ unsigned short sA[16][264];
    const int tid = threadIdx.x;
    const int lane = tid & 63, wave = tid >> 6;
    const int l15 = lane & 15, hi = lane >> 4;
    const int cbase = wave * 64;
    const int row0 = blockIdx.x * 16;
    {   // load hid -> sR
        const int r = tid >> 4, cb = (tid & 15) * 4;
        #pragma unroll
        for (int q = 0; q < 4; ++q)
            *(float4*)&sR[r][cb + q*64] =
                *(const float4*)(hid + (size_t)(row0+r)*256 + cb + q*64);
    }
    __syncthreads();
    #pragma unroll
    for (int it = 0; it < 2; ++it){
        const float* g  = it ? g1  : g0;
        const float* be = it ? be1 : be0;
        const float* B1 = it ? b11 : b10;
        const float* B2 = it ? b21 : b20;
        const unsigned short* W1 = Wtb + (size_t)(it ? 2 : 0)*65536;
        const unsigned short* W2 = Wtb + (size_t)(it ? 3 : 1)*65536;
        {   // LN(sR) -> sA bf16; wave owns rows wave*4+j
            float4 gg = *(const float4*)(g + lane*4);
            float4 bb = *(const float4*)(be + lane*4);
            #pragma unroll
            for (int j = 0; j < 4; ++j){
                const int r = wave*4 + j;
                float4 v = *(const float4*)&sR[r][lane*4];
                float s = v.x+v.y+v.z+v.w;
                float q = v.x*v.x+v.y*v.y+v.z*v.z+v.w*v.w;
                #pragma unroll
                for (int m = 1; m < 64; m <<= 1){
                    s += __shfl_xor(s, m, 64); q += __shfl_xor(q, m, 64);
                }
                float mu = s*(1.f/256.f);
                float rs = rsqrtf(q*(1.f/256.f) - mu*mu + 1e-5f);
                ushort4 o;
                o.x = f2bf((v.x-mu)*rs*gg.x+bb.x);
                o.y = f2bf((v.y-mu)*rs*gg.y+bb.y);
                o.z = f2bf((v.z-mu)*rs*gg.z+bb.z);
                o.w = f2bf((v.w-mu)*rs*gg.w+bb.w);
                *(ushort4*)&sA[r][lane*4] = o;
            }
        }
        __syncthreads();
        {   // GEMM1 + gelu -> sA
            f32x4 acc[4];
            #pragma unroll
            for (int t = 0; t < 4; ++t){ acc[t][0]=0.f; acc[t][1]=0.f; acc[t][2]=0.f; acc[t][3]=0.f; }
            mfma_gemm16(sA, W1, l15, hi, cbase, acc);
            #pragma unroll
            for (int t = 0; t < 4; ++t){
                int ct = cbase + t*16 + l15;
                float bbx = B1[ct];
                #pragma unroll
                for (int j = 0; j < 4; ++j)
                    sA[hi*4 + j][ct] = f2bf(gelu_t(acc[t][j] + bbx));
            }
        }
        __syncthreads();
        {   // GEMM2 + bias + residual -> sR
            f32x4 acc[4];
            #pragma unroll
            for (int t = 0; t < 4; ++t){ acc[t][0]=0.f; acc[t][1]=0.f; acc[t][2]=0.f; acc[t][3]=0.f; }
            mfma_gemm16(sA, W2, l15, hi, cbase, acc);
            #pragma unroll
            for (int t = 0; t < 4; ++t){
                int ct = cbase + t*16 + l15;
                float bbx = B2[ct];
                #pragma unroll
                for (int j = 0; j < 4; ++j)
                    sR[hi*4 + j][ct] += acc[t][j] + bbx;
            }
        }
        __syncthreads();
    }
    {   // write hid back
        const int r = tid >> 4, cb = (tid & 15) * 4;
        #pragma unroll
        for (int q = 0; q < 4; ++q)
            *(float4*)(hid + (size_t)(row0+r)*256 + cb + q*64) =
                *(const float4*)&sR[r][cb + q*64];
    }
    {   // hh = LN(hid)*hg + hb (f32)
        float4 gg = *(const float4*)(hg + lane*4);
        float4 bb = *(const float4*)(hb + lane*4);
        #pragma unroll
        for (int j = 0; j < 4; ++j){
            const int r = wave*4 + j;
            float4 v = *(const float4*)&sR[r][lane*4];
            float s = v.x+v.y+v.z+v.w;
            float q = v.x*v.x+v.y*v.y+v.z*v.z+v.w*v.w;
            #pragma unroll
            for (int m = 1; m < 64; m <<= 1){
                s += __shfl_xor(s, m, 64); q += __shfl_xor(q, m, 64);
            }
            float mu = s*(1.f/256.f);
            float rs = rsqrtf(q*(1.f/256.f) - mu*mu + 1e-5f);
            float4 o = make_float4((v.x-mu)*rs*gg.x+bb.x, (v.y-mu)*rs*gg.y+bb.y,
                                   (v.z-mu)*rs*gg.z+bb.z, (v.w-mu)*rs*gg.w+bb.w);
            *(float4*)(hh_out + (size_t)(row0+r)*256 + lane*4) = o;
        }
    }
}

// rc = relu(Hn @ Hn^T), tiled GEMM. Grid (63, 4, batches_in_chunk).
__global__ __launch_bounds__(256) void k_corr(const float* __restrict__ HnTc,
                                              float* __restrict__ rcb)
{
    __shared__ float sA[64][32];
    __shared__ float sB[64][128];
    const int tid = threadIdx.x;
    const float* H = HnTc + (size_t)blockIdx.z * 64 * N;
    float* rc = rcb + (size_t)blockIdx.z * N * N;
    const int n0 = blockIdx.x * 32;
    const int cs = blockIdx.y * 512;
    const int ce = (cs + 512 < N) ? cs + 512 : N;
    #pragma unroll
    for (int j = 0; j < 8; ++j){
        int idx = tid + 256*j;
        int k = idx >> 5, r = idx & 31;
        int nn = n0 + r;
        sA[k][r] = (nn < N) ? H[(size_t)k*N + nn] : 0.f;
    }
    const int trow = tid >> 6;
    const int tcol = tid & 63;
    for (int mc = cs; mc < ce; mc += 128){
        __syncthreads();
        #pragma unroll
        for (int q = 0; q < 8; ++q){
            int f = tid + 256*q;
            int k = f >> 5, c4 = (f & 31) * 4;
            int m = mc + c4;
            float4 v = (m + 3 < N) ? *(const float4*)(H + (size_t)k*N + m)
                                   : make_float4(0.f,0.f,0.f,0.f);
            *(float4*)&sB[k][c4] = v;
        }
        __syncthreads();
        float acc[8][2];
        #pragma unroll
        for (int r = 0; r < 8; ++r){ acc[r][0] = 0.f; acc[r][1] = 0.f; }
        #pragma unroll 4
        for (int k = 0; k < 64; ++k){
            float2 b2v = *(const float2*)&sB[k][tcol*2];
            float4 a0 = *(const float4*)&sA[k][trow*8];
            float4 a1 = *(const float4*)&sA[k][trow*8 + 4];
            float av[8] = {a0.x,a0.y,a0.z,a0.w,a1.x,a1.y,a1.z,a1.w};
            #pragma unroll
            for (int r = 0; r < 8; ++r){
                acc[r][0] = fmaf(av[r], b2v.x, acc[r][0]);
                acc[r][1] = fmaf(av[r], b2v.y, acc[r][1]);
            }
        }
        int m = mc + tcol*2;
        if (m < N){
            #pragma unroll
            for (int r = 0; r < 8; ++r){
                int nn = n0 + trow*8 + r;
                if (nn < N){
                    float2 o = make_float2(fmaxf(acc[r][0],0.f), fmaxf(acc[r][1],0.f));
                    *(float2*)(rc + (size_t)nn*N + m) = o;
                }
            }
        }
    }
}

// Per-row selection (softmax + 2x top-20) and sparse aggregation.
// ONE ROW PER WAVE, 4 rows per block. All LDS handoffs fenced by uniform
// __syncthreads(). Candidate mapping m = 4*lane + 256*i + j (float4 rc loads;
// top-k exactness is independent of the lane->candidate mapping).
__global__ __launch_bounds__(256) void k_select(
    const float* __restrict__ rcb, const float* __restrict__ Zn,
    const float* __restrict__ hh, const float* __restrict__ mix_logit,
    float* __restrict__ msg, int row_base)
{
    __shared__ float cl[4][128];
    __shared__ int   lm[4][64];
    __shared__ float lv[4][64];
    const int tid = threadIdx.x;
    const int lane = tid & 63, wv = tid >> 6;
    const int rloc = blockIdx.x * 4 + wv;   // row within this rc chunk
    const int n = row_base + rloc;          // global row
    const int base = (n / N) * N;
    const float* rcrow = rcb + (size_t)rloc * N;
    float* clw = cl[wv];
    // own row's Zn -> SGPRs (wave-uniform)
    float zr[16];
    {
        const float* zp = Zn + (size_t)n * 16;
        #pragma unroll
        for (int q = 0; q < 16; ++q)
            zr[q] = __uint_as_float(__builtin_amdgcn_readfirstlane(__float_as_uint(zp[q])));
    }
    float e_[32], rc_[32];
    float sumE = 0.f, sumC = 0.f;
    #pragma unroll
    for (int i = 0; i < 8; ++i){
        const int m4 = 4*lane + 256*i;    // N % 4 == 0: float4 never straddles
        float4 rv = make_float4(-1.f, -1.f, -1.f, -1.f);
        if (m4 < N){
            rv = *(const float4*)(rcrow + m4);
            sumC += rv.x + rv.y + rv.z + rv.w;
        }
        rc_[4*i+0] = rv.x; rc_[4*i+1] = rv.y; rc_[4*i+2] = rv.z; rc_[4*i+3] = rv.w;
        #pragma unroll
        for (int j = 0; j < 4; ++j){
            const int m = m4 + j;
            float e = 0.f;
            if (m4 < N){
                const float4* zp = (const float4*)(Zn + (size_t)(base + m) * 16);
                float4 za = zp[0], zb = zp[1], zc = zp[2], zd = zp[3];
                float s = za.x * zr[0];
                s = fmaf(za.y, zr[1], s);  s = fmaf(za.z, zr[2], s);  s = fmaf(za.w, zr[3], s);
                s = fmaf(zb.x, zr[4], s);  s = fmaf(zb.y, zr[5], s);  s = fmaf(zb.z, zr[6], s);
                s = fmaf(zb.w, zr[7], s);  s = fmaf(zc.x, zr[8], s);  s = fmaf(zc.y, zr[9], s);
                s = fmaf(zc.z, zr[10], s); s = fmaf(zc.w, zr[11], s); s = fmaf(zd.x, zr[12], s);
                s = fmaf(zd.y, zr[13], s); s = fmaf(zd.z, zr[14], s); s = fmaf(zd.w, zr[15], s);
                e = __expf(s);            // |s| <= 1, safe without max-subtraction
                sumE += e;
            }
            e_[4*i+j] = e;
        }
    }
    #pragma unroll
    for (int mm = 1; mm < 64; mm <<= 1){
        sumE += __shfl_xor(sumE, mm, 64);
        sumC += __shfl_xor(sumC, mm, 64);
    }
    float c_kth = wave_topk20_sync(rc_, clw);
    float skl = 0.f;
    #pragma unroll
    for (int i = 0; i < 32; ++i){ if (rc_[i] >= c_kth) skl += rc_[i]; }
    #pragma unroll
    for (int mm = 1; mm < 64; mm <<= 1) skl += __shfl_xor(skl, mm, 64);
    const float invSumExp = 1.f / sumE;
    const float r1 = 1.f / (sumC + EPSF);
    const float rollsc = r1 * (1.f / (skl * r1 + EPSF));
    const float mixw = 1.f / (1.f + __expf(-mix_logit[0]));
    const float onemix = 1.f - mixw;
    float sumAm = 0.f;
    #pragma unroll
    for (int i = 0; i < 32; ++i){       // e_ becomes am in place
        float am = -1.f;
        if (rc_[i] >= 0.f){
            float afdg  = e_[i] * invSumExp;
            float aroll = (rc_[i] >= c_kth) ? rc_[i] * rollsc : 0.f;
            am = fmaf(mixw, afdg, onemix * aroll);
            sumAm += am;
        }
        e_[i] = am;
    }
    #pragma unroll
    for (int mm = 1; mm < 64; mm <<= 1) sumAm += __shfl_xor(sumAm, mm, 64);
    float am_kth = wave_topk20_sync(e_, clw);
    float sk2 = 0.f;
    #pragma unroll
    for (int i = 0; i < 32; ++i){ if (e_[i] >= am_kth) sk2 += e_[i]; }
    #pragma unroll
    for (int mm = 1; mm < 64; mm <<= 1) sk2 += __shfl_xor(sk2, mm, 64);
    const float ra = 1.f / (sumAm + EPSF);
    const float fsc = ra * (1.f / (sk2 * ra + EPSF));
    // deterministic compaction of kept entries into this wave's list
    unsigned keep = 0; int cnt = 0;
    #pragma unroll
    for (int i = 0; i < 32; ++i){
        bool kp = (e_[i] >= am_kth) && (e_[i] > 0.f);
        if (kp){ keep |= (1u << i); cnt++; }
    }
    int incl = cnt;
    #pragma unroll
    for (int s = 1; s < 64; s <<= 1){
        int o = __shfl_up(incl, s, 64);
        if (lane >= s) incl += o;
    }
    int total = __shfl(incl, 63, 64);
    if (total > 64) total = 64;
    int offs = incl - cnt;
    #pragma unroll
    for (int i = 0; i < 32; ++i){
        if (keep & (1u << i)){
            if (offs < 64){
                lm[wv][offs] = 4*lane + 256*(i >> 2) + (i & 3);
                lv[wv][offs] = e_[i] * fsc;
            }
            offs++;
        }
    }
    __syncthreads();                    // uniform: fences lm/lv writes
    // msg[n, lane*4 .. +3] = sum_kept w * hh[m, :]
    float a0 = 0.f, a1 = 0.f, a2 = 0.f, a3 = 0.f;
    for (int i = 0; i < total; ++i){
        float w = lv[wv][i];
        const float4 hv = *(const float4*)(hh + ((size_t)(base + lm[wv][i]))*256 + lane*4);
        a0 = fmaf(w, hv.x, a0); a1 = fmaf(w, hv.y, a1);
        a2 = fmaf(w, hv.z, a2); a3 = fmaf(w, hv.w, a3);
    }
    *(float4*)(msg + (size_t)n*256 + lane*4) = make_float4(a0, a1, a2, a3);
}

// Graph-residual MLP + head. MFMA bf16. 16 rows/block, 500 blocks.
__global__ __launch_bounds__(256) void k_gblk(
    const float* __restrict__ hid, const float* __restrict__ msgb,
    const unsigned short* __restrict__ Wtb,
    const float* __restrict__ b1, const float* __restrict__ b2,
    const float* __restrict__ hg, const float* __restrict__ hb,
    const float* __restrict__ hw, const float* __restrict__ hbias,
    float* __restrict__ y)
{
    __shared__ float sR[16][264];
    __shared__ unsigned short sA[16][264];
    const int tid = threadIdx.x;
    const int lane = tid & 63, wave = tid >> 6;
    const int l15 = lane & 15, hi = lane >> 4;
    const int cbase = wave * 64;
    const int row0 = blockIdx.x * 16;
    {   // hid -> sR (f32), msg -> sA (bf16)
        const int r = tid >> 4, cb = (tid & 15) * 4;
        #pragma unroll
        for (int q = 0; q < 4; ++q){
            *(float4*)&sR[r][cb + q*64] =
                *(const float4*)(hid + (size_t)(row0+r)*256 + cb + q*64);
            float4 mv = *(const float4*)(msgb + (size_t)(row0+r)*256 + cb + q*64);
            ushort4 u;
            u.x = f2bf(mv.x); u.y = f2bf(mv.y); u.z = f2bf(mv.z); u.w = f2bf(mv.w);
            *(ushort4*)&sA[r][cb + q*64] = u;
        }
    }
    __syncthreads();
    {   // GEMM1 + gelu -> sA
        f32x4 acc[4];
        #pragma unroll
        for (int t = 0; t < 4; ++t){ acc[t][0]=0.f; acc[t][1]=0.f; acc[t][2]=0.f; acc[t][3]=0.f; }
        mfma_gemm16(sA, Wtb + (size_t)4*65536, l15, hi, cbase, acc);
        #pragma unroll
        for (int t = 0; t < 4; ++t){
            int ct = cbase + t*16 + l15;
            float bbx = b1[ct];
            #pragma unroll
            for (int j = 0; j < 4; ++j)
                sA[hi*4 + j][ct] = f2bf(gelu_t(acc[t][j] + bbx));
        }
    }
    __syncthreads();
    {   // GEMM2 + bias + residual -> sR
        f32x4 acc[4];
        #pragma unroll
        for (int t = 0; t < 4; ++t){ acc[t][0]=0.f; acc[t][1]=0.f; acc[t][2]=0.f; acc[t][3]=0.f; }
        mfma_gemm16(sA, Wtb + (size_t)5*65536, l15, hi, cbase, acc);
        #pragma unroll
        for (int t = 0; t < 4; ++t){
            int ct = cbase + t*16 + l15;
            float bbx = b2[ct];
            #pragma unroll
            for (int j = 0; j < 4; ++j)
                sR[hi*4 + j][ct] += acc[t][j] + bbx;
        }
    }
    __syncthreads();
    {   // head: y = gelu(LN(sR)) @ head_w + head_b; wave owns rows wave*4+j
        float4 gg = *(const float4*)(hg + lane*4);
        float4 bb = *(const float4*)(hb + lane*4);
        float4 wv = *(const float4*)(hw + lane*4);
        #pragma unroll
        for (int j = 0; j < 4; ++j){
            const int r = wave*4 + j;
            float4 v = *(const float4*)&sR[r][lane*4];
            float s = v.x+v.y+v.z+v.w;
            float q = v.x*v.x+v.y*v.y+v.z*v.z+v.w*v.w;
            #pragma unroll
            for (int m = 1; m < 64; m <<= 1){
                s += __shfl_xor(s, m, 64); q += __shfl_xor(q, m, 64);
            }
            float mu = s*(1.f/256.f);
            float rs = rsqrtf(q*(1.f/256.f) - mu*mu + 1e-5f);
            float p = gelu_t((v.x-mu)*rs*gg.x+bb.x)*wv.x
                    + gelu_t((v.y-mu)*rs*gg.y+bb.y)*wv.y
                    + gelu_t((v.z-mu)*rs*gg.z+bb.z)*wv.z
                    + gelu_t((v.w-mu)*rs*gg.w+bb.w)*wv.w;
            #pragma unroll
            for (int m = 1; m < 64; m <<= 1) p += __shfl_xor(p, m, 64);
            if (lane == 0) y[row0 + r] = p + hbias[0];
        }
    }
}

// ---------------- launch ----------------

extern "C" void kernel_launch(void* const* d_in, const int* in_sizes, int n_in,
                              void* d_out, int out_size, void* d_ws, size_t ws_size,
                              hipStream_t stream)
{
    (void)in_sizes; (void)n_in; (void)out_size;
    const float* X         = (const float*)d_in[0];
    const float* history   = (const float*)d_in[2];
    const float* enc_ln_g  = (const float*)d_in[3];
    const float* enc_ln_b  = (const float*)d_in[4];
    const float* enc_w1    = (const float*)d_in[5];
    const float* enc_b1    = (const float*)d_in[6];
    const float* enc_w2    = (const float*)d_in[7];
    const float* enc_b2    = (const float*)d_in[8];
    const float* proj_w    = (const float*)d_in[9];
    const float* proj_b    = (const float*)d_in[10];
    const float* fdg_B     = (const float*)d_in[11];
    const float* mixlog    = (const float*)d_in[12];
    const float* gblk_ln_g = (const float*)d_in[13];
    const float* gblk_ln_b = (const float*)d_in[14];
    const float* gblk_w1   = (const float*)d_in[15];
    const float* gblk_b1   = (const float*)d_in[16];
    const float* gblk_w2   = (const float*)d_in[17];
    const float* gblk_b2   = (const float*)d_in[18];
    const float* head_ln_g = (const float*)d_in[19];
    const float* head_ln_b = (const float*)d_in[20];
    const float* head_w    = (const float*)d_in[21];
    const float* head_b    = (const float*)d_in[22];

    float* ws  = (float*)d_ws;
    float* hid = ws;                              // 2,048,000 f
    float* hh  = hid + (size_t)NROWS*DH;          // 2,048,000 f
    float* msg = hh  + (size_t)NROWS*DH;          // 2,048,000 f
    float* Znb = msg + (size_t)NROWS*DH;          //   128,000 f
    float* HnT = Znb + (size_t)NROWS*16;          //   512,000 f
    unsigned short* Wtb = (unsigned short*)(HnT + (size_t)NB*64*N);  // 6*65536 us
    float* rcbuf = (float*)(Wtb + (size_t)6*65536);
    float* y   = (float*)d_out;

    const size_t baseF = (size_t)3*NROWS*DH + (size_t)NROWS*16 + (size_t)NB*64*N
                       + (size_t)6*65536/2;
    const size_t perBatchF = (size_t)N*N;
    size_t availF = (ws_size/4 > baseF) ? (ws_size/4 - baseF) : perBatchF;
    int bpc = (availF >= 4*perBatchF) ? 4 : (availF >= 2*perBatchF) ? 2 : 1;

    k_wcvt<<<dim3(8,8,6), 256, 0, stream>>>(
        (const float*)d_in[25], (const float*)d_in[27],
        (const float*)d_in[31], (const float*)d_in[33],
        gblk_w1, gblk_w2, Wtb);
    k_enc<<<NROWS/8, 256, 0, stream>>>(X, enc_ln_g, enc_ln_b, enc_w1, enc_b1, enc_w2, enc_b2,
                                       proj_w, proj_b, fdg_B, hid, Znb);
    k_hist<<<NROWS/4, 256, 0, stream>>>(history, HnT);
    k_mlp2<<<NROWS/16, 256, 0, stream>>>(hid, Wtb,
        (const float*)d_in[23], (const float*)d_in[24],
        (const float*)d_in[26], (const float*)d_in[28],
        (const float*)d_in[29], (const float*)d_in[30],
        (const float*)d_in[32], (const float*)d_in[34],
        gblk_ln_g, gblk_ln_b, hh);
    for (int cb = 0; cb < NB; cb += bpc){
        dim3 g1(63, 4, bpc);
        k_corr<<<g1, 256, 0, stream>>>(HnT + (size_t)cb*64*N, rcbuf);
        k_select<<<bpc*N/4, 256, 0, stream>>>(rcbuf, Znb, hh, mixlog, msg, cb*N);
    }
    k_gblk<<<NROWS/16, 256, 0, stream>>>(hid, msg, Wtb, gblk_b1, gblk_b2,
                                         head_ln_g, head_ln_b, head_w, head_b, y);
}

// Round 13
// 238.539 us; speedup vs baseline: 1.6009x; 1.6009x over previous
//
#include <hip/hip_runtime.h>
#include <math.h>

#define NB 4
#define N 2000
#define DIN 128
#define DH 256
#define NROWS (NB*N)          // 8000
#define EPSF 1e-8f

typedef __attribute__((ext_vector_type(8))) short bf16x8;
typedef __attribute__((ext_vector_type(4))) float f32x4;

// ---------------- helpers ----------------

__device__ __forceinline__ float gelu_t(float x){
    // jax.nn.gelu approximate=True (tanh form)
    float z = 0.7978845608028654f * fmaf(0.044715f * x * x, x, x);
    z = fminf(fmaxf(z, -20.f), 20.f);
    float e = __expf(2.f * z);
    return 0.5f * x * (1.f + (e - 1.f) / (e + 1.f));
}

__device__ __forceinline__ unsigned short f2bf(float f){   // RNE f32->bf16 bits
    unsigned u = __float_as_uint(f);
    return (unsigned short)((u + 0x7FFFu + ((u >> 16) & 1u)) >> 16);
}

// full descending bitonic sort of 64 values across a wave (lane 0 = largest)
__device__ __forceinline__ float wave_sort64_desc(float v){
    const int lane = threadIdx.x & 63;
    #pragma unroll
    for (int k = 2; k <= 64; k <<= 1){
        #pragma unroll
        for (int j = k >> 1; j >= 1; j >>= 1){
            float o = __shfl_xor(v, j, 64);
            bool keepMax = ((lane & k) == 0) == ((lane & j) == 0);
            v = keepMax ? fmaxf(v, o) : fminf(v, o);
        }
    }
    return v;
}

// descending bitonic sort of 128 values (2 regs/lane; element idx = 2*lane+r)
__device__ __forceinline__ void sort128_desc(float &v0, float &v1){
    const int lane = threadIdx.x & 63;
    #pragma unroll
    for (int k = 2; k <= 128; k <<= 1){
        #pragma unroll
        for (int j = k >> 1; j >= 2; j >>= 1){
            int lj = j >> 1;
            float o0 = __shfl_xor(v0, lj, 64);
            float o1 = __shfl_xor(v1, lj, 64);
            int idx0 = 2*lane, idx1 = 2*lane + 1;
            bool km0 = ((idx0 & k) == 0) == ((idx0 & j) == 0);
            bool km1 = ((idx1 & k) == 0) == ((idx1 & j) == 0);
            v0 = km0 ? fmaxf(v0, o0) : fminf(v0, o0);
            v1 = km1 ? fmaxf(v1, o1) : fminf(v1, o1);
        }
        {   // j == 1: within-lane CAS
            bool up = (((2*lane) & k) == 0);
            float a = fmaxf(v0, v1), b = fminf(v0, v1);
            v0 = up ? a : b;
            v1 = up ? b : a;
        }
    }
}

// Non-destructive wave-local exact 20th-largest (with multiplicity) fallback:
// descending distinct-value extraction; <=20 iterations; register-only.
__device__ __forceinline__ float wave_topk20_slow32(const float (&v)[32]){
    float cur = 1e30f, kth = 0.f;
    int consumed = 0;
    for (int it = 0; it < 20; ++it){
        if (consumed >= 20) break;
        float bm = -3.f;
        #pragma unroll
        for (int i = 0; i < 32; ++i){ if (v[i] < cur) bm = fmaxf(bm, v[i]); }
        #pragma unroll
        for (int mm = 1; mm < 64; mm <<= 1) bm = fmaxf(bm, __shfl_xor(bm, mm, 64));
        int c = 0;
        #pragma unroll
        for (int i = 0; i < 32; ++i) c += (v[i] == bm) ? 1 : 0;
        #pragma unroll
        for (int mm = 1; mm < 64; mm <<= 1) c += __shfl_xor(c, mm, 64);
        consumed += c;
        kth = bm;
        cur = bm;
    }
    return kth;
}

// Exact wave-local 20th-largest (with multiplicity) of 64 lanes x 32 regs.
// cl: this wave's private 128-float LDS region. MUST be called by ALL
// threads of the block at the same program point: the two __syncthreads()
// are uniform (outside any divergent branch). Three paths by candidate
// count (wave-uniform choice): <=64 -> 21-stage sort64 (expected case,
// E[total]~22), <=128 -> sort128, else register fallback.
__device__ __forceinline__ float wave_topk20_sync(const float (&v)[32], float* cl){
    const int lane = threadIdx.x & 63;
    float mx = v[0];
    #pragma unroll
    for (int i = 1; i < 32; ++i) mx = fmaxf(mx, v[i]);
    float sm = wave_sort64_desc(mx);
    float u = __shfl(sm, 19, 64);       // 20th-largest lane-max: u <= true kth
    int cnt = 0;
    #pragma unroll
    for (int i = 0; i < 32; ++i) cnt += (v[i] >= u) ? 1 : 0;
    int incl = cnt;
    #pragma unroll
    for (int s = 1; s < 64; s <<= 1){
        int o = __shfl_up(incl, s, 64);
        if (lane >= s) incl += o;
    }
    const int total = __shfl(incl, 63, 64);   // >= 20 by construction of u
    const bool fast = (total <= 128);   // wave-uniform
    if (fast){
        int offs = incl - cnt;
        #pragma unroll
        for (int i = 0; i < 32; ++i){
            if (v[i] >= u) cl[offs++] = v[i];
        }
    }
    __syncthreads();                    // uniform: fences candidate writes
    float kth;
    if (total <= 64){                   // short path: single-reg bitonic sort
        float c0 = (lane < total) ? cl[lane] : -3.f;
        c0 = wave_sort64_desc(c0);
        kth = __shfl(c0, 19, 64);       // element index 19
    } else if (fast){
        float c0 = (2*lane     < total) ? cl[2*lane]     : -3.f;
        float c1 = (2*lane + 1 < total) ? cl[2*lane + 1] : -3.f;
        sort128_desc(c0, c1);
        kth = __shfl(c1, 9, 64);        // element index 19
    } else {
        kth = wave_topk20_slow32(v);
    }
    __syncthreads();                    // uniform: cl safe to reuse after return
    return kth;
}

// Per-wave MFMA GEMM: out16x64 = A(16x256, bf16 LDS) @ Wt-slice.
// Wt is [col][k] bf16. Wave covers cols cbase..cbase+63 as 4 16-col tiles.
// Internal barrier after A-frag loads => caller may overwrite sA after return.
__device__ __forceinline__ void mfma_gemm16(
    const unsigned short (*__restrict__ sA)[264], const unsigned short* __restrict__ Wt,
    int l15, int hi, int cbase, f32x4 acc[4])
{
    bf16x8 a[8];
    #pragma unroll
    for (int kb = 0; kb < 8; ++kb)
        a[kb] = *(const bf16x8*)&sA[l15][kb*32 + hi*8];
    __syncthreads();                     // all waves' A-frags in regs
    const unsigned short* wp0 = Wt + (size_t)(cbase      + l15)*256 + hi*8;
    const unsigned short* wp1 = Wt + (size_t)(cbase + 16 + l15)*256 + hi*8;
    const unsigned short* wp2 = Wt + (size_t)(cbase + 32 + l15)*256 + hi*8;
    const unsigned short* wp3 = Wt + (size_t)(cbase + 48 + l15)*256 + hi*8;
    #pragma unroll
    for (int kb = 0; kb < 8; ++kb){
        bf16x8 b0 = *(const bf16x8*)(wp0 + kb*32);
        bf16x8 b1 = *(const bf16x8*)(wp1 + kb*32);
        bf16x8 b2 = *(const bf16x8*)(wp2 + kb*32);
        bf16x8 b3 = *(const bf16x8*)(wp3 + kb*32);
        acc[0] = __builtin_amdgcn_mfma_f32_16x16x32_bf16(a[kb], b0, acc[0], 0, 0, 0);
        acc[1] = __builtin_amdgcn_mfma_f32_16x16x32_bf16(a[kb], b1, acc[1], 0, 0, 0);
        acc[2] = __builtin_amdgcn_mfma_f32_16x16x32_bf16(a[kb], b2, acc[2], 0, 0, 0);
        acc[3] = __builtin_amdgcn_mfma_f32_16x16x32_bf16(a[kb], b3, acc[3], 0, 0, 0);
    }
}

// ---------------- kernels ----------------

// Weight prep: Wt[m][c][k] = bf16(W[m][k][c]), 6 matrices 256x256. Grid (8,8,6).
__global__ __launch_bounds__(256) void k_wcvt(
    const float* __restrict__ w10, const float* __restrict__ w20,
    const float* __restrict__ w11, const float* __restrict__ w21,
    const float* __restrict__ gw1, const float* __restrict__ gw2,
    unsigned short* __restrict__ Wt)
{
    __shared__ float t[32][33];
    const int m = blockIdx.z;
    const float* W = (m==0)?w10:(m==1)?w20:(m==2)?w11:(m==3)?w21:(m==4)?gw1:gw2;
    unsigned short* out = Wt + (size_t)m*65536;
    const int k0 = blockIdx.y*32, c0 = blockIdx.x*32;
    const int tx = threadIdx.x & 31, ty = threadIdx.x >> 5;
    #pragma unroll
    for (int j = 0; j < 4; ++j){
        int k = ty*4 + j;
        t[k][tx] = W[(size_t)(k0+k)*256 + c0+tx];
    }
    __syncthreads();
    #pragma unroll
    for (int j = 0; j < 4; ++j){
        int c = ty*4 + j;
        out[(size_t)(c0+c)*256 + k0+tx] = f2bf(t[tx][c]);
    }
}

// Encoder bottleneck + projection + FDG embedding. 8 rows/block, 1000 blocks.
__global__ __launch_bounds__(256) void k_enc(
    const float* __restrict__ X,
    const float* __restrict__ lg, const float* __restrict__ lb,
    const float* __restrict__ w1, const float* __restrict__ b1,
    const float* __restrict__ w2, const float* __restrict__ b2,
    const float* __restrict__ pw, const float* __restrict__ pb,
    const float* __restrict__ fB,
    float* __restrict__ hid, float* __restrict__ Zn)
{
    __shared__ float sH[8][132];
    __shared__ float sT[8][68];
    __shared__ float sXm[8][132];
    const int tid = threadIdx.x;
    const int lane = tid & 63;
    const int wave = tid >> 6;
    const int rg = wave * 2;
    const int row0 = blockIdx.x * 8;
    const int cx = lane * 2;
    float2 x0 = *(const float2*)(X + (size_t)(row0+rg  )*128 + cx);
    float2 x1 = *(const float2*)(X + (size_t)(row0+rg+1)*128 + cx);
    {   // LN over 128 (two rows per wave, full-wave reduce)
        float sa = x0.x + x0.y, sb = x1.x + x1.y;
        float qa = x0.x*x0.x + x0.y*x0.y, qb = x1.x*x1.x + x1.y*x1.y;
        #pragma unroll
        for (int m = 1; m < 64; m <<= 1){
            sa += __shfl_xor(sa, m, 64); sb += __shfl_xor(sb, m, 64);
            qa += __shfl_xor(qa, m, 64); qb += __shfl_xor(qb, m, 64);
        }
        float mua = sa*(1.f/128.f), mub = sb*(1.f/128.f);
        float rsa = rsqrtf(qa*(1.f/128.f) - mua*mua + 1e-5f);
        float rsb = rsqrtf(qb*(1.f/128.f) - mub*mub + 1e-5f);
        float2 gg = *(const float2*)(lg + cx);
        float2 bb = *(const float2*)(lb + cx);
        sH[rg  ][cx] = (x0.x - mua)*rsa*gg.x + bb.x;
        sH[rg  ][cx+1] = (x0.y - mua)*rsa*gg.y + bb.y;
        sH[rg+1][cx] = (x1.x - mub)*rsb*gg.x + bb.x;
        sH[rg+1][cx+1] = (x1.y - mub)*rsb*gg.y + bb.y;
    }
    __syncthreads();
    {   // GEMM1 (128->64): one col per lane, two rows
        float a0 = 0.f, a1 = 0.f;
        #pragma unroll 4
        for (int k = 0; k < 128; ++k){
            float h0 = sH[rg][k], h1 = sH[rg+1][k];
            float wk = w1[k*64 + lane];
            a0 = fmaf(h0, wk, a0);
            a1 = fmaf(h1, wk, a1);
        }
        float bb = b1[lane];
        sT[rg  ][lane] = gelu_t(a0 + bb);
        sT[rg+1][lane] = gelu_t(a1 + bb);
    }
    __syncthreads();
    {   // GEMM2 (64->128): Xm = X + t@w2 + b2 -> sXm
        float p0x=0.f,p0y=0.f,p1x=0.f,p1y=0.f;
        #pragma unroll 4
        for (int k = 0; k < 64; ++k){
            float t0 = sT[rg][k], t1 = sT[rg+1][k];
            float2 w = *(const float2*)(w2 + k*128 + cx);
            p0x = fmaf(t0, w.x, p0x); p0y = fmaf(t0, w.y, p0y);
            p1x = fmaf(t1, w.x, p1x); p1y = fmaf(t1, w.y, p1y);
        }
        float2 bb = *(const float2*)(b2 + cx);
        sXm[rg  ][cx]   = x0.x + p0x + bb.x;
        sXm[rg  ][cx+1] = x0.y + p0y + bb.y;
        sXm[rg+1][cx]   = x1.x + p1x + bb.x;
        sXm[rg+1][cx+1] = x1.y + p1y + bb.y;
    }
    __syncthreads();
    {   // GEMM3: hid = Xm @ proj_w + proj_b, col-split per wave (64 cols each)
        const int ri = lane >> 4;
        const int wc = wave*64 + (lane & 15)*4;
        float a0[4] = {0,0,0,0}, a1[4] = {0,0,0,0};
        #pragma unroll 4
        for (int k = 0; k < 128; ++k){
            float h0 = sXm[ri*2][k], h1 = sXm[ri*2+1][k];
            float4 w = *(const float4*)(pw + k*256 + wc);
            a0[0]=fmaf(h0,w.x,a0[0]); a0[1]=fmaf(h0,w.y,a0[1]); a0[2]=fmaf(h0,w.z,a0[2]); a0[3]=fmaf(h0,w.w,a0[3]);
            a1[0]=fmaf(h1,w.x,a1[0]); a1[1]=fmaf(h1,w.y,a1[1]); a1[2]=fmaf(h1,w.z,a1[2]); a1[3]=fmaf(h1,w.w,a1[3]);
        }
        float4 bb = *(const float4*)(pb + wc);
        float4 o0 = make_float4(a0[0]+bb.x, a0[1]+bb.y, a0[2]+bb.z, a0[3]+bb.w);
        float4 o1 = make_float4(a1[0]+bb.x, a1[1]+bb.y, a1[2]+bb.z, a1[3]+bb.w);
        *(float4*)(hid + (size_t)(row0+ri*2  )*256 + wc) = o0;
        *(float4*)(hid + (size_t)(row0+ri*2+1)*256 + wc) = o1;
    }
    if (tid < 128){   // Z = Xm @ fdg_B^T ; Zn = Z/(||Z||+eps)
        const int r = tid >> 4, q = tid & 15;
        float z = 0.f;
        #pragma unroll 4
        for (int k = 0; k < 128; ++k) z = fmaf(sXm[r][k], fB[q*128 + k], z);
        float s2 = z*z;
        #pragma unroll
        for (int m = 1; m < 16; m <<= 1) s2 += __shfl_xor(s2, m, 64);
        Zn[(size_t)(row0 + r)*16 + q] = z / (sqrtf(s2) + EPSF);
    }
}

// history -> normalized (pre-scaled by 1/8), stored TRANSPOSED: HnT[b][t][n]
__global__ __launch_bounds__(256) void k_hist(const float* __restrict__ H, float* __restrict__ HnT)
{
    const int row  = blockIdx.x * 4 + (threadIdx.x >> 6);
    const int lane = threadIdx.x & 63;
    float v = H[(size_t)row*64 + lane];
    float s = v;
    #pragma unroll
    for (int mm = 1; mm < 64; mm <<= 1) s += __shfl_xor(s, mm, 64);
    float mu = s * (1.f/64.f);
    float d = v - mu;
    float s2 = d*d;
    #pragma unroll
    for (int mm = 1; mm < 64; mm <<= 1) s2 += __shfl_xor(s2, mm, 64);
    float sd = sqrtf(s2 * (1.f/64.f));
    const int b = row / N, nloc = row % N;
    HnT[(size_t)b*64*N + (size_t)lane*N + nloc] = d / ((sd + EPSF) * 8.f);
}

// Fused residual MLP blocks 0+1 + gblk-LN (hh). MFMA bf16. 16 rows/block.
__global__ __launch_bounds__(256) void k_mlp2(
    float* __restrict__ hid, const unsigned short* __restrict__ Wtb,
    const float* __restrict__ g0, const float* __restrict__ be0,
    const float* __restrict__ b10, const float* __restrict__ b20,
    const float* __restrict__ g1, const float* __restrict__ be1,
    const float* __restrict__ b11, const float* __restrict__ b21,
    const float* __restrict__ hg, const float* __restrict__ hb,
    float* __restrict__ hh_out)
{
    __shared__ float sR[16][264];
    __shared__ unsigned short sA[16][264];
    const int tid = threadIdx.x;
    const int lane = tid & 63, wave = tid >> 6;
    const int l15 = lane & 15, hi = lane >> 4;
    const int cbase = wave * 64;
    const int row0 = blockIdx.x * 16;
    {   // load hid -> sR
        const int r = tid >> 4, cb = (tid & 15) * 4;
        #pragma unroll
        for (int q = 0; q < 4; ++q)
            *(float4*)&sR[r][cb + q*64] =
                *(const float4*)(hid + (size_t)(row0+r)*256 + cb + q*64);
    }
    __syncthreads();
    #pragma unroll
    for (int it = 0; it < 2; ++it){
        const float* g  = it ? g1  : g0;
        const float* be = it ? be1 : be0;
        const float* B1 = it ? b11 : b10;
        const float* B2 = it ? b21 : b20;
        const unsigned short* W1 = Wtb + (size_t)(it ? 2 : 0)*65536;
        const unsigned short* W2 = Wtb + (size_t)(it ? 3 : 1)*65536;
        {   // LN(sR) -> sA bf16; wave owns rows wave*4+j
            float4 gg = *(const float4*)(g + lane*4);
            float4 bb = *(const float4*)(be + lane*4);
            #pragma unroll
            for (int j = 0; j < 4; ++j){
                const int r = wave*4 + j;
                float4 v = *(const float4*)&sR[r][lane*4];
                float s = v.x+v.y+v.z+v.w;
                float q = v.x*v.x+v.y*v.y+v.z*v.z+v.w*v.w;
                #pragma unroll
                for (int m = 1; m < 64; m <<= 1){
                    s += __shfl_xor(s, m, 64); q += __shfl_xor(q, m, 64);
                }
                float mu = s*(1.f/256.f);
                float rs = rsqrtf(q*(1.f/256.f) - mu*mu + 1e-5f);
                ushort4 o;
                o.x = f2bf((v.x-mu)*rs*gg.x+bb.x);
                o.y = f2bf((v.y-mu)*rs*gg.y+bb.y);
                o.z = f2bf((v.z-mu)*rs*gg.z+bb.z);
                o.w = f2bf((v.w-mu)*rs*gg.w+bb.w);
                *(ushort4*)&sA[r][lane*4] = o;
            }
        }
        __syncthreads();
        {   // GEMM1 + gelu -> sA
            f32x4 acc[4];
            #pragma unroll
            for (int t = 0; t < 4; ++t){ acc[t][0]=0.f; acc[t][1]=0.f; acc[t][2]=0.f; acc[t][3]=0.f; }
            mfma_gemm16(sA, W1, l15, hi, cbase, acc);
            #pragma unroll
            for (int t = 0; t < 4; ++t){
                int ct = cbase + t*16 + l15;
                float bbx = B1[ct];
                #pragma unroll
                for (int j = 0; j < 4; ++j)
                    sA[hi*4 + j][ct] = f2bf(gelu_t(acc[t][j] + bbx));
            }
        }
        __syncthreads();
        {   // GEMM2 + bias + residual -> sR
            f32x4 acc[4];
            #pragma unroll
            for (int t = 0; t < 4; ++t){ acc[t][0]=0.f; acc[t][1]=0.f; acc[t][2]=0.f; acc[t][3]=0.f; }
            mfma_gemm16(sA, W2, l15, hi, cbase, acc);
            #pragma unroll
            for (int t = 0; t < 4; ++t){
                int ct = cbase + t*16 + l15;
                float bbx = B2[ct];
                #pragma unroll
                for (int j = 0; j < 4; ++j)
                    sR[hi*4 + j][ct] += acc[t][j] + bbx;
            }
        }
        __syncthreads();
    }
    {   // write hid back
        const int r = tid >> 4, cb = (tid & 15) * 4;
        #pragma unroll
        for (int q = 0; q < 4; ++q)
            *(float4*)(hid + (size_t)(row0+r)*256 + cb + q*64) =
                *(const float4*)&sR[r][cb + q*64];
    }
    {   // hh = LN(hid)*hg + hb (f32)
        float4 gg = *(const float4*)(hg + lane*4);
        float4 bb = *(const float4*)(hb + lane*4);
        #pragma unroll
        for (int j = 0; j < 4; ++j){
            const int r = wave*4 + j;
            float4 v = *(const float4*)&sR[r][lane*4];
            float s = v.x+v.y+v.z+v.w;
            float q = v.x*v.x+v.y*v.y+v.z*v.z+v.w*v.w;
            #pragma unroll
            for (int m = 1; m < 64; m <<= 1){
                s += __shfl_xor(s, m, 64); q += __shfl_xor(q, m, 64);
            }
            float mu = s*(1.f/256.f);
            float rs = rsqrtf(q*(1.f/256.f) - mu*mu + 1e-5f);
            float4 o = make_float4((v.x-mu)*rs*gg.x+bb.x, (v.y-mu)*rs*gg.y+bb.y,
                                   (v.z-mu)*rs*gg.z+bb.z, (v.w-mu)*rs*gg.w+bb.w);
            *(float4*)(hh_out + (size_t)(row0+r)*256 + lane*4) = o;
        }
    }
}

// rc = relu(Hn @ Hn^T), tiled GEMM. Grid (63, 4, batches_in_chunk).
__global__ __launch_bounds__(256) void k_corr(const float* __restrict__ HnTc,
                                              float* __restrict__ rcb)
{
    __shared__ float sA[64][32];
    __shared__ float sB[64][128];
    const int tid = threadIdx.x;
    const float* H = HnTc + (size_t)blockIdx.z * 64 * N;
    float* rc = rcb + (size_t)blockIdx.z * N * N;
    const int n0 = blockIdx.x * 32;
    const int cs = blockIdx.y * 512;
    const int ce = (cs + 512 < N) ? cs + 512 : N;
    #pragma unroll
    for (int j = 0; j < 8; ++j){
        int idx = tid + 256*j;
        int k = idx >> 5, r = idx & 31;
        int nn = n0 + r;
        sA[k][r] = (nn < N) ? H[(size_t)k*N + nn] : 0.f;
    }
    const int trow = tid >> 6;
    const int tcol = tid & 63;
    for (int mc = cs; mc < ce; mc += 128){
        __syncthreads();
        #pragma unroll
        for (int q = 0; q < 8; ++q){
            int f = tid + 256*q;
            int k = f >> 5, c4 = (f & 31) * 4;
            int m = mc + c4;
            float4 v = (m + 3 < N) ? *(const float4*)(H + (size_t)k*N + m)
                                   : make_float4(0.f,0.f,0.f,0.f);
            *(float4*)&sB[k][c4] = v;
        }
        __syncthreads();
        float acc[8][2];
        #pragma unroll
        for (int r = 0; r < 8; ++r){ acc[r][0] = 0.f; acc[r][1] = 0.f; }
        #pragma unroll 4
        for (int k = 0; k < 64; ++k){
            float2 b2v = *(const float2*)&sB[k][tcol*2];
            float4 a0 = *(const float4*)&sA[k][trow*8];
            float4 a1 = *(const float4*)&sA[k][trow*8 + 4];
            float av[8] = {a0.x,a0.y,a0.z,a0.w,a1.x,a1.y,a1.z,a1.w};
            #pragma unroll
            for (int r = 0; r < 8; ++r){
                acc[r][0] = fmaf(av[r], b2v.x, acc[r][0]);
                acc[r][1] = fmaf(av[r], b2v.y, acc[r][1]);
            }
        }
        int m = mc + tcol*2;
        if (m < N){
            #pragma unroll
            for (int r = 0; r < 8; ++r){
                int nn = n0 + trow*8 + r;
                if (nn < N){
                    float2 o = make_float2(fmaxf(acc[r][0],0.f), fmaxf(acc[r][1],0.f));
                    *(float2*)(rc + (size_t)nn*N + m) = o;
                }
            }
        }
    }
}

// Per-row selection (softmax + 2x top-20) and sparse aggregation.
// ONE ROW PER WAVE, 4 rows per block. All LDS handoffs are fenced by
// uniform __syncthreads() (every thread executes the same barrier sequence).
__global__ __launch_bounds__(256) void k_select(
    const float* __restrict__ rcb, const float* __restrict__ Zn,
    const float* __restrict__ hh, const float* __restrict__ mix_logit,
    float* __restrict__ msg, int row_base)
{
    __shared__ float cl[4][128];
    __shared__ int   lm[4][64];
    __shared__ float lv[4][64];
    const int tid = threadIdx.x;
    const int lane = tid & 63, wv = tid >> 6;
    const int rloc = blockIdx.x * 4 + wv;   // row within this rc chunk
    const int n = row_base + rloc;          // global row
    const int base = (n / N) * N;
    const float* rcrow = rcb + (size_t)rloc * N;
    float* clw = cl[wv];
    float zr[16];
    {   // own row's Zn (wave-uniform)
        const float4* zp = (const float4*)(Zn + (size_t)n * 16);
        float4 z0 = zp[0], z1 = zp[1], z2 = zp[2], z3 = zp[3];
        zr[0]=z0.x; zr[1]=z0.y; zr[2]=z0.z; zr[3]=z0.w;
        zr[4]=z1.x; zr[5]=z1.y; zr[6]=z1.z; zr[7]=z1.w;
        zr[8]=z2.x; zr[9]=z2.y; zr[10]=z2.z; zr[11]=z2.w;
        zr[12]=z3.x; zr[13]=z3.y; zr[14]=z3.z; zr[15]=z3.w;
    }
    float e_[32], rc_[32];
    float sumE = 0.f, sumC = 0.f;
    #pragma unroll
    for (int i = 0; i < 32; ++i){
        const int m = lane + 64*i;
        float rcv = -1.f, e = 0.f;
        if (m < N){
            rcv = rcrow[m];
            const float4* zp = (const float4*)(Zn + (size_t)(base + m) * 16);
            float4 za = zp[0], zb = zp[1], zc = zp[2], zd = zp[3];
            float s = za.x * zr[0];
            s = fmaf(za.y, zr[1], s);  s = fmaf(za.z, zr[2], s);  s = fmaf(za.w, zr[3], s);
            s = fmaf(zb.x, zr[4], s);  s = fmaf(zb.y, zr[5], s);  s = fmaf(zb.z, zr[6], s);
            s = fmaf(zb.w, zr[7], s);  s = fmaf(zc.x, zr[8], s);  s = fmaf(zc.y, zr[9], s);
            s = fmaf(zc.z, zr[10], s); s = fmaf(zc.w, zr[11], s); s = fmaf(zd.x, zr[12], s);
            s = fmaf(zd.y, zr[13], s); s = fmaf(zd.z, zr[14], s); s = fmaf(zd.w, zr[15], s);
            e = __expf(s);             // |s| <= 1, safe without max-subtraction
            sumE += e; sumC += rcv;
        }
        e_[i] = e; rc_[i] = rcv;
    }
    #pragma unroll
    for (int mm = 1; mm < 64; mm <<= 1){
        sumE += __shfl_xor(sumE, mm, 64);
        sumC += __shfl_xor(sumC, mm, 64);
    }
    float c_kth = wave_topk20_sync(rc_, clw);
    float skl = 0.f;
    #pragma unroll
    for (int i = 0; i < 32; ++i){ if (rc_[i] >= c_kth) skl += rc_[i]; }
    #pragma unroll
    for (int mm = 1; mm < 64; mm <<= 1) skl += __shfl_xor(skl, mm, 64);
    const float invSumExp = 1.f / sumE;
    const float r1 = 1.f / (sumC + EPSF);
    const float rollsc = r1 * (1.f / (skl * r1 + EPSF));
    const float mixw = 1.f / (1.f + __expf(-mix_logit[0]));
    const float onemix = 1.f - mixw;
    float sumAm = 0.f;
    #pragma unroll
    for (int i = 0; i < 32; ++i){       // e_ becomes am in place
        float am = -1.f;
        if (rc_[i] >= 0.f){
            float afdg  = e_[i] * invSumExp;
            float aroll = (rc_[i] >= c_kth) ? rc_[i] * rollsc : 0.f;
            am = fmaf(mixw, afdg, onemix * aroll);
            sumAm += am;
        }
        e_[i] = am;
    }
    #pragma unroll
    for (int mm = 1; mm < 64; mm <<= 1) sumAm += __shfl_xor(sumAm, mm, 64);
    float am_kth = wave_topk20_sync(e_, clw);
    float sk2 = 0.f;
    #pragma unroll
    for (int i = 0; i < 32; ++i){ if (e_[i] >= am_kth) sk2 += e_[i]; }
    #pragma unroll
    for (int mm = 1; mm < 64; mm <<= 1) sk2 += __shfl_xor(sk2, mm, 64);
    const float ra = 1.f / (sumAm + EPSF);
    const float fsc = ra * (1.f / (sk2 * ra + EPSF));
    // deterministic compaction of kept entries into this wave's list
    unsigned keep = 0; int cnt = 0;
    #pragma unroll
    for (int i = 0; i < 32; ++i){
        bool kp = (e_[i] >= am_kth) && (e_[i] > 0.f);
        if (kp){ keep |= (1u << i); cnt++; }
    }
    int incl = cnt;
    #pragma unroll
    for (int s = 1; s < 64; s <<= 1){
        int o = __shfl_up(incl, s, 64);
        if (lane >= s) incl += o;
    }
    int total = __shfl(incl, 63, 64);
    if (total > 64) total = 64;
    int offs = incl - cnt;
    #pragma unroll
    for (int i = 0; i < 32; ++i){
        if (keep & (1u << i)){
            if (offs < 64){ lm[wv][offs] = lane + 64*i; lv[wv][offs] = e_[i] * fsc; }
            offs++;
        }
    }
    __syncthreads();                    // uniform: fences lm/lv writes
    // msg[n, lane*4 .. +3] = sum_kept w * hh[m, :]
    float a0 = 0.f, a1 = 0.f, a2 = 0.f, a3 = 0.f;
    for (int i = 0; i < total; ++i){
        float w = lv[wv][i];
        const float4 hv = *(const float4*)(hh + ((size_t)(base + lm[wv][i]))*256 + lane*4);
        a0 = fmaf(w, hv.x, a0); a1 = fmaf(w, hv.y, a1);
        a2 = fmaf(w, hv.z, a2); a3 = fmaf(w, hv.w, a3);
    }
    *(float4*)(msg + (size_t)n*256 + lane*4) = make_float4(a0, a1, a2, a3);
}

// Graph-residual MLP + head. MFMA bf16. 16 rows/block, 500 blocks.
__global__ __launch_bounds__(256) void k_gblk(
    const float* __restrict__ hid, const float* __restrict__ msgb,
    const unsigned short* __restrict__ Wtb,
    const float* __restrict__ b1, const float* __restrict__ b2,
    const float* __restrict__ hg, const float* __restrict__ hb,
    const float* __restrict__ hw, const float* __restrict__ hbias,
    float* __restrict__ y)
{
    __shared__ float sR[16][264];
    __shared__ unsigned short sA[16][264];
    const int tid = threadIdx.x;
    const int lane = tid & 63, wave = tid >> 6;
    const int l15 = lane & 15, hi = lane >> 4;
    const int cbase = wave * 64;
    const int row0 = blockIdx.x * 16;
    {   // hid -> sR (f32), msg -> sA (bf16)
        const int r = tid >> 4, cb = (tid & 15) * 4;
        #pragma unroll
        for (int q = 0; q < 4; ++q){
            *(float4*)&sR[r][cb + q*64] =
                *(const float4*)(hid + (size_t)(row0+r)*256 + cb + q*64);
            float4 mv = *(const float4*)(msgb + (size_t)(row0+r)*256 + cb + q*64);
            ushort4 u;
            u.x = f2bf(mv.x); u.y = f2bf(mv.y); u.z = f2bf(mv.z); u.w = f2bf(mv.w);
            *(ushort4*)&sA[r][cb + q*64] = u;
        }
    }
    __syncthreads();
    {   // GEMM1 + gelu -> sA
        f32x4 acc[4];
        #pragma unroll
        for (int t = 0; t < 4; ++t){ acc[t][0]=0.f; acc[t][1]=0.f; acc[t][2]=0.f; acc[t][3]=0.f; }
        mfma_gemm16(sA, Wtb + (size_t)4*65536, l15, hi, cbase, acc);
        #pragma unroll
        for (int t = 0; t < 4; ++t){
            int ct = cbase + t*16 + l15;
            float bbx = b1[ct];
            #pragma unroll
            for (int j = 0; j < 4; ++j)
                sA[hi*4 + j][ct] = f2bf(gelu_t(acc[t][j] + bbx));
        }
    }
    __syncthreads();
    {   // GEMM2 + bias + residual -> sR
        f32x4 acc[4];
        #pragma unroll
        for (int t = 0; t < 4; ++t){ acc[t][0]=0.f; acc[t][1]=0.f; acc[t][2]=0.f; acc[t][3]=0.f; }
        mfma_gemm16(sA, Wtb + (size_t)5*65536, l15, hi, cbase, acc);
        #pragma unroll
        for (int t = 0; t < 4; ++t){
            int ct = cbase + t*16 + l15;
            float bbx = b2[ct];
            #pragma unroll
            for (int j = 0; j < 4; ++j)
                sR[hi*4 + j][ct] += acc[t][j] + bbx;
        }
    }
    __syncthreads();
    {   // head: y = gelu(LN(sR)) @ head_w + head_b; wave owns rows wave*4+j
        float4 gg = *(const float4*)(hg + lane*4);
        float4 bb = *(const float4*)(hb + lane*4);
        float4 wv = *(const float4*)(hw + lane*4);
        #pragma unroll
        for (int j = 0; j < 4; ++j){
            const int r = wave*4 + j;
            float4 v = *(const float4*)&sR[r][lane*4];
            float s = v.x+v.y+v.z+v.w;
            float q = v.x*v.x+v.y*v.y+v.z*v.z+v.w*v.w;
            #pragma unroll
            for (int m = 1; m < 64; m <<= 1){
                s += __shfl_xor(s, m, 64); q += __shfl_xor(q, m, 64);
            }
            float mu = s*(1.f/256.f);
            float rs = rsqrtf(q*(1.f/256.f) - mu*mu + 1e-5f);
            float p = gelu_t((v.x-mu)*rs*gg.x+bb.x)*wv.x
                    + gelu_t((v.y-mu)*rs*gg.y+bb.y)*wv.y
                    + gelu_t((v.z-mu)*rs*gg.z+bb.z)*wv.z
                    + gelu_t((v.w-mu)*rs*gg.w+bb.w)*wv.w;
            #pragma unroll
            for (int m = 1; m < 64; m <<= 1) p += __shfl_xor(p, m, 64);
            if (lane == 0) y[row0 + r] = p + hbias[0];
        }
    }
}

// ---------------- launch ----------------

extern "C" void kernel_launch(void* const* d_in, const int* in_sizes, int n_in,
                              void* d_out, int out_size, void* d_ws, size_t ws_size,
                              hipStream_t stream)
{
    (void)in_sizes; (void)n_in; (void)out_size;
    const float* X         = (const float*)d_in[0];
    const float* history   = (const float*)d_in[2];
    const float* enc_ln_g  = (const float*)d_in[3];
    const float* enc_ln_b  = (const float*)d_in[4];
    const float* enc_w1    = (const float*)d_in[5];
    const float* enc_b1    = (const float*)d_in[6];
    const float* enc_w2    = (const float*)d_in[7];
    const float* enc_b2    = (const float*)d_in[8];
    const float* proj_w    = (const float*)d_in[9];
    const float* proj_b    = (const float*)d_in[10];
    const float* fdg_B     = (const float*)d_in[11];
    const float* mixlog    = (const float*)d_in[12];
    const float* gblk_ln_g = (const float*)d_in[13];
    const float* gblk_ln_b = (const float*)d_in[14];
    const float* gblk_w1   = (const float*)d_in[15];
    const float* gblk_b1   = (const float*)d_in[16];
    const float* gblk_w2   = (const float*)d_in[17];
    const float* gblk_b2   = (const float*)d_in[18];
    const float* head_ln_g = (const float*)d_in[19];
    const float* head_ln_b = (const float*)d_in[20];
    const float* head_w    = (const float*)d_in[21];
    const float* head_b    = (const float*)d_in[22];

    float* ws  = (float*)d_ws;
    float* hid = ws;                              // 2,048,000 f
    float* hh  = hid + (size_t)NROWS*DH;          // 2,048,000 f
    float* msg = hh  + (size_t)NROWS*DH;          // 2,048,000 f
    float* Znb = msg + (size_t)NROWS*DH;          //   128,000 f
    float* HnT = Znb + (size_t)NROWS*16;          //   512,000 f
    unsigned short* Wtb = (unsigned short*)(HnT + (size_t)NB*64*N);  // 6*65536 us
    float* rcbuf = (float*)(Wtb + (size_t)6*65536);
    float* y   = (float*)d_out;

    const size_t baseF = (size_t)3*NROWS*DH + (size_t)NROWS*16 + (size_t)NB*64*N
                       + (size_t)6*65536/2;
    const size_t perBatchF = (size_t)N*N;
    size_t availF = (ws_size/4 > baseF) ? (ws_size/4 - baseF) : perBatchF;
    int bpc = (availF >= 4*perBatchF) ? 4 : (availF >= 2*perBatchF) ? 2 : 1;

    k_wcvt<<<dim3(8,8,6), 256, 0, stream>>>(
        (const float*)d_in[25], (const float*)d_in[27],
        (const float*)d_in[31], (const float*)d_in[33],
        gblk_w1, gblk_w2, Wtb);
    k_enc<<<NROWS/8, 256, 0, stream>>>(X, enc_ln_g, enc_ln_b, enc_w1, enc_b1, enc_w2, enc_b2,
                                       proj_w, proj_b, fdg_B, hid, Znb);
    k_hist<<<NROWS/4, 256, 0, stream>>>(history, HnT);
    k_mlp2<<<NROWS/16, 256, 0, stream>>>(hid, Wtb,
        (const float*)d_in[23], (const float*)d_in[24],
        (const float*)d_in[26], (const float*)d_in[28],
        (const float*)d_in[29], (const float*)d_in[30],
        (const float*)d_in[32], (const float*)d_in[34],
        gblk_ln_g, gblk_ln_b, hh);
    for (int cb = 0; cb < NB; cb += bpc){
        dim3 g1(63, 4, bpc);
        k_corr<<<g1, 256, 0, stream>>>(HnT + (size_t)cb*64*N, rcbuf);
        k_select<<<bpc*N/4, 256, 0, stream>>>(rcbuf, Znb, hh, mixlog, msg, cb*N);
    }
    k_gblk<<<NROWS/16, 256, 0, stream>>>(hid, msg, Wtb, gblk_b1, gblk_b2,
                                         head_ln_g, head_ln_b, head_w, head_b, y);
}

// Round 14
// 235.890 us; speedup vs baseline: 1.6189x; 1.0112x over previous
//
#include <hip/hip_runtime.h>
#include <math.h>

#define NB 4
#define N 2000
#define DIN 128
#define DH 256
#define NROWS (NB*N)          // 8000
#define EPSF 1e-8f

typedef __attribute__((ext_vector_type(8))) short bf16x8;
typedef __attribute__((ext_vector_type(4))) float f32x4;

// ---------------- helpers ----------------

__device__ __forceinline__ float gelu_t(float x){
    // jax.nn.gelu approximate=True (tanh form)
    float z = 0.7978845608028654f * fmaf(0.044715f * x * x, x, x);
    z = fminf(fmaxf(z, -20.f), 20.f);
    float e = __expf(2.f * z);
    return 0.5f * x * (1.f + (e - 1.f) / (e + 1.f));
}

__device__ __forceinline__ unsigned short f2bf(float f){   // RNE f32->bf16 bits
    unsigned u = __float_as_uint(f);
    return (unsigned short)((u + 0x7FFFu + ((u >> 16) & 1u)) >> 16);
}

// full descending bitonic sort of 64 values across a wave (lane 0 = largest)
__device__ __forceinline__ float wave_sort64_desc(float v){
    const int lane = threadIdx.x & 63;
    #pragma unroll
    for (int k = 2; k <= 64; k <<= 1){
        #pragma unroll
        for (int j = k >> 1; j >= 1; j >>= 1){
            float o = __shfl_xor(v, j, 64);
            bool keepMax = ((lane & k) == 0) == ((lane & j) == 0);
            v = keepMax ? fmaxf(v, o) : fminf(v, o);
        }
    }
    return v;
}

// descending bitonic sort of 128 values (2 regs/lane; element idx = 2*lane+r)
__device__ __forceinline__ void sort128_desc(float &v0, float &v1){
    const int lane = threadIdx.x & 63;
    #pragma unroll
    for (int k = 2; k <= 128; k <<= 1){
        #pragma unroll
        for (int j = k >> 1; j >= 2; j >>= 1){
            int lj = j >> 1;
            float o0 = __shfl_xor(v0, lj, 64);
            float o1 = __shfl_xor(v1, lj, 64);
            int idx0 = 2*lane, idx1 = 2*lane + 1;
            bool km0 = ((idx0 & k) == 0) == ((idx0 & j) == 0);
            bool km1 = ((idx1 & k) == 0) == ((idx1 & j) == 0);
            v0 = km0 ? fmaxf(v0, o0) : fminf(v0, o0);
            v1 = km1 ? fmaxf(v1, o1) : fminf(v1, o1);
        }
        {   // j == 1: within-lane CAS
            bool up = (((2*lane) & k) == 0);
            float a = fmaxf(v0, v1), b = fminf(v0, v1);
            v0 = up ? a : b;
            v1 = up ? b : a;
        }
    }
}

// Non-destructive wave-local exact 20th-largest (with multiplicity) fallback:
// descending distinct-value extraction; <=20 iterations; register-only.
__device__ __forceinline__ float wave_topk20_slow32(const float (&v)[32]){
    float cur = 1e30f, kth = 0.f;
    int consumed = 0;
    for (int it = 0; it < 20; ++it){
        if (consumed >= 20) break;
        float bm = -3.f;
        #pragma unroll
        for (int i = 0; i < 32; ++i){ if (v[i] < cur) bm = fmaxf(bm, v[i]); }
        #pragma unroll
        for (int mm = 1; mm < 64; mm <<= 1) bm = fmaxf(bm, __shfl_xor(bm, mm, 64));
        int c = 0;
        #pragma unroll
        for (int i = 0; i < 32; ++i) c += (v[i] == bm) ? 1 : 0;
        #pragma unroll
        for (int mm = 1; mm < 64; mm <<= 1) c += __shfl_xor(c, mm, 64);
        consumed += c;
        kth = bm;
        cur = bm;
    }
    return kth;
}

// Exact wave-local 20th-largest (with multiplicity) of 64 lanes x 32 regs.
// cl: this wave's private 128-float LDS region. MUST be called by ALL
// threads of the block at the same program point: the two __syncthreads()
// are uniform (outside any divergent branch). Three paths by candidate
// count (wave-uniform choice): <=64 -> 21-stage sort64 (expected case,
// E[total]~22), <=128 -> sort128, else register fallback.
__device__ __forceinline__ float wave_topk20_sync(const float (&v)[32], float* cl){
    const int lane = threadIdx.x & 63;
    float mx = v[0];
    #pragma unroll
    for (int i = 1; i < 32; ++i) mx = fmaxf(mx, v[i]);
    float sm = wave_sort64_desc(mx);
    float u = __shfl(sm, 19, 64);       // 20th-largest lane-max: u <= true kth
    int cnt = 0;
    #pragma unroll
    for (int i = 0; i < 32; ++i) cnt += (v[i] >= u) ? 1 : 0;
    int incl = cnt;
    #pragma unroll
    for (int s = 1; s < 64; s <<= 1){
        int o = __shfl_up(incl, s, 64);
        if (lane >= s) incl += o;
    }
    const int total = __shfl(incl, 63, 64);   // >= 20 by construction of u
    const bool fast = (total <= 128);   // wave-uniform
    if (fast){
        int offs = incl - cnt;
        #pragma unroll
        for (int i = 0; i < 32; ++i){
            if (v[i] >= u) cl[offs++] = v[i];
        }
    }
    __syncthreads();                    // uniform: fences candidate writes
    float kth;
    if (total <= 64){                   // short path: single-reg bitonic sort
        float c0 = (lane < total) ? cl[lane] : -3.f;
        c0 = wave_sort64_desc(c0);
        kth = __shfl(c0, 19, 64);       // element index 19
    } else if (fast){
        float c0 = (2*lane     < total) ? cl[2*lane]     : -3.f;
        float c1 = (2*lane + 1 < total) ? cl[2*lane + 1] : -3.f;
        sort128_desc(c0, c1);
        kth = __shfl(c1, 9, 64);        // element index 19
    } else {
        kth = wave_topk20_slow32(v);
    }
    __syncthreads();                    // uniform: cl safe to reuse after return
    return kth;
}

// Per-wave MFMA GEMM: out16x64 = A(16x256, bf16 LDS) @ Wt-slice.
// Wt is [col][k] bf16. Wave covers cols cbase..cbase+63 as 4 16-col tiles.
// Internal barrier after A-frag loads => caller may overwrite sA after return.
__device__ __forceinline__ void mfma_gemm16(
    const unsigned short (*__restrict__ sA)[264], const unsigned short* __restrict__ Wt,
    int l15, int hi, int cbase, f32x4 acc[4])
{
    bf16x8 a[8];
    #pragma unroll
    for (int kb = 0; kb < 8; ++kb)
        a[kb] = *(const bf16x8*)&sA[l15][kb*32 + hi*8];
    __syncthreads();                     // all waves' A-frags in regs
    const unsigned short* wp0 = Wt + (size_t)(cbase      + l15)*256 + hi*8;
    const unsigned short* wp1 = Wt + (size_t)(cbase + 16 + l15)*256 + hi*8;
    const unsigned short* wp2 = Wt + (size_t)(cbase + 32 + l15)*256 + hi*8;
    const unsigned short* wp3 = Wt + (size_t)(cbase + 48 + l15)*256 + hi*8;
    #pragma unroll
    for (int kb = 0; kb < 8; ++kb){
        bf16x8 b0 = *(const bf16x8*)(wp0 + kb*32);
        bf16x8 b1 = *(const bf16x8*)(wp1 + kb*32);
        bf16x8 b2 = *(const bf16x8*)(wp2 + kb*32);
        bf16x8 b3 = *(const bf16x8*)(wp3 + kb*32);
        acc[0] = __builtin_amdgcn_mfma_f32_16x16x32_bf16(a[kb], b0, acc[0], 0, 0, 0);
        acc[1] = __builtin_amdgcn_mfma_f32_16x16x32_bf16(a[kb], b1, acc[1], 0, 0, 0);
        acc[2] = __builtin_amdgcn_mfma_f32_16x16x32_bf16(a[kb], b2, acc[2], 0, 0, 0);
        acc[3] = __builtin_amdgcn_mfma_f32_16x16x32_bf16(a[kb], b3, acc[3], 0, 0, 0);
    }
}

// ---------------- kernels ----------------

// Weight prep: Wt[m][c][k] = bf16(W[m][k][c]), 6 matrices 256x256. Grid (8,8,6).
__global__ __launch_bounds__(256) void k_wcvt(
    const float* __restrict__ w10, const float* __restrict__ w20,
    const float* __restrict__ w11, const float* __restrict__ w21,
    const float* __restrict__ gw1, const float* __restrict__ gw2,
    unsigned short* __restrict__ Wt)
{
    __shared__ float t[32][33];
    const int m = blockIdx.z;
    const float* W = (m==0)?w10:(m==1)?w20:(m==2)?w11:(m==3)?w21:(m==4)?gw1:gw2;
    unsigned short* out = Wt + (size_t)m*65536;
    const int k0 = blockIdx.y*32, c0 = blockIdx.x*32;
    const int tx = threadIdx.x & 31, ty = threadIdx.x >> 5;
    #pragma unroll
    for (int j = 0; j < 4; ++j){
        int k = ty*4 + j;
        t[k][tx] = W[(size_t)(k0+k)*256 + c0+tx];
    }
    __syncthreads();
    #pragma unroll
    for (int j = 0; j < 4; ++j){
        int c = ty*4 + j;
        out[(size_t)(c0+c)*256 + k0+tx] = f2bf(t[tx][c]);
    }
}

// Encoder bottleneck + projection + FDG embedding. 8 rows/block, 1000 blocks.
__global__ __launch_bounds__(256) void k_enc(
    const float* __restrict__ X,
    const float* __restrict__ lg, const float* __restrict__ lb,
    const float* __restrict__ w1, const float* __restrict__ b1,
    const float* __restrict__ w2, const float* __restrict__ b2,
    const float* __restrict__ pw, const float* __restrict__ pb,
    const float* __restrict__ fB,
    float* __restrict__ hid, float* __restrict__ Zn)
{
    __shared__ float sH[8][132];
    __shared__ float sT[8][68];
    __shared__ float sXm[8][132];
    const int tid = threadIdx.x;
    const int lane = tid & 63;
    const int wave = tid >> 6;
    const int rg = wave * 2;
    const int row0 = blockIdx.x * 8;
    const int cx = lane * 2;
    float2 x0 = *(const float2*)(X + (size_t)(row0+rg  )*128 + cx);
    float2 x1 = *(const float2*)(X + (size_t)(row0+rg+1)*128 + cx);
    {   // LN over 128 (two rows per wave, full-wave reduce)
        float sa = x0.x + x0.y, sb = x1.x + x1.y;
        float qa = x0.x*x0.x + x0.y*x0.y, qb = x1.x*x1.x + x1.y*x1.y;
        #pragma unroll
        for (int m = 1; m < 64; m <<= 1){
            sa += __shfl_xor(sa, m, 64); sb += __shfl_xor(sb, m, 64);
            qa += __shfl_xor(qa, m, 64); qb += __shfl_xor(qb, m, 64);
        }
        float mua = sa*(1.f/128.f), mub = sb*(1.f/128.f);
        float rsa = rsqrtf(qa*(1.f/128.f) - mua*mua + 1e-5f);
        float rsb = rsqrtf(qb*(1.f/128.f) - mub*mub + 1e-5f);
        float2 gg = *(const float2*)(lg + cx);
        float2 bb = *(const float2*)(lb + cx);
        sH[rg  ][cx] = (x0.x - mua)*rsa*gg.x + bb.x;
        sH[rg  ][cx+1] = (x0.y - mua)*rsa*gg.y + bb.y;
        sH[rg+1][cx] = (x1.x - mub)*rsb*gg.x + bb.x;
        sH[rg+1][cx+1] = (x1.y - mub)*rsb*gg.y + bb.y;
    }
    __syncthreads();
    {   // GEMM1 (128->64): one col per lane, two rows
        float a0 = 0.f, a1 = 0.f;
        #pragma unroll 4
        for (int k = 0; k < 128; ++k){
            float h0 = sH[rg][k], h1 = sH[rg+1][k];
            float wk = w1[k*64 + lane];
            a0 = fmaf(h0, wk, a0);
            a1 = fmaf(h1, wk, a1);
        }
        float bb = b1[lane];
        sT[rg  ][lane] = gelu_t(a0 + bb);
        sT[rg+1][lane] = gelu_t(a1 + bb);
    }
    __syncthreads();
    {   // GEMM2 (64->128): Xm = X + t@w2 + b2 -> sXm
        float p0x=0.f,p0y=0.f,p1x=0.f,p1y=0.f;
        #pragma unroll 4
        for (int k = 0; k < 64; ++k){
            float t0 = sT[rg][k], t1 = sT[rg+1][k];
            float2 w = *(const float2*)(w2 + k*128 + cx);
            p0x = fmaf(t0, w.x, p0x); p0y = fmaf(t0, w.y, p0y);
            p1x = fmaf(t1, w.x, p1x); p1y = fmaf(t1, w.y, p1y);
        }
        float2 bb = *(const float2*)(b2 + cx);
        sXm[rg  ][cx]   = x0.x + p0x + bb.x;
        sXm[rg  ][cx+1] = x0.y + p0y + bb.y;
        sXm[rg+1][cx]   = x1.x + p1x + bb.x;
        sXm[rg+1][cx+1] = x1.y + p1y + bb.y;
    }
    __syncthreads();
    {   // GEMM3: hid = Xm @ proj_w + proj_b, col-split per wave (64 cols each)
        const int ri = lane >> 4;
        const int wc = wave*64 + (lane & 15)*4;
        float a0[4] = {0,0,0,0}, a1[4] = {0,0,0,0};
        #pragma unroll 4
        for (int k = 0; k < 128; ++k){
            float h0 = sXm[ri*2][k], h1 = sXm[ri*2+1][k];
            float4 w = *(const float4*)(pw + k*256 + wc);
            a0[0]=fmaf(h0,w.x,a0[0]); a0[1]=fmaf(h0,w.y,a0[1]); a0[2]=fmaf(h0,w.z,a0[2]); a0[3]=fmaf(h0,w.w,a0[3]);
            a1[0]=fmaf(h1,w.x,a1[0]); a1[1]=fmaf(h1,w.y,a1[1]); a1[2]=fmaf(h1,w.z,a1[2]); a1[3]=fmaf(h1,w.w,a1[3]);
        }
        float4 bb = *(const float4*)(pb + wc);
        float4 o0 = make_float4(a0[0]+bb.x, a0[1]+bb.y, a0[2]+bb.z, a0[3]+bb.w);
        float4 o1 = make_float4(a1[0]+bb.x, a1[1]+bb.y, a1[2]+bb.z, a1[3]+bb.w);
        *(float4*)(hid + (size_t)(row0+ri*2  )*256 + wc) = o0;
        *(float4*)(hid + (size_t)(row0+ri*2+1)*256 + wc) = o1;
    }
    if (tid < 128){   // Z = Xm @ fdg_B^T ; Zn = Z/(||Z||+eps)
        const int r = tid >> 4, q = tid & 15;
        float z = 0.f;
        #pragma unroll 4
        for (int k = 0; k < 128; ++k) z = fmaf(sXm[r][k], fB[q*128 + k], z);
        float s2 = z*z;
        #pragma unroll
        for (int m = 1; m < 16; m <<= 1) s2 += __shfl_xor(s2, m, 64);
        Zn[(size_t)(row0 + r)*16 + q] = z / (sqrtf(s2) + EPSF);
    }
}

// history -> normalized (pre-scaled by 1/8), stored TRANSPOSED: HnT[b][t][n]
__global__ __launch_bounds__(256) void k_hist(const float* __restrict__ H, float* __restrict__ HnT)
{
    const int row  = blockIdx.x * 4 + (threadIdx.x >> 6);
    const int lane = threadIdx.x & 63;
    float v = H[(size_t)row*64 + lane];
    float s = v;
    #pragma unroll
    for (int mm = 1; mm < 64; mm <<= 1) s += __shfl_xor(s, mm, 64);
    float mu = s * (1.f/64.f);
    float d = v - mu;
    float s2 = d*d;
    #pragma unroll
    for (int mm = 1; mm < 64; mm <<= 1) s2 += __shfl_xor(s2, mm, 64);
    float sd = sqrtf(s2 * (1.f/64.f));
    const int b = row / N, nloc = row % N;
    HnT[(size_t)b*64*N + (size_t)lane*N + nloc] = d / ((sd + EPSF) * 8.f);
}

// Fused residual MLP blocks 0+1 + gblk-LN (hh). MFMA bf16. 16 rows/block.
__global__ __launch_bounds__(256) void k_mlp2(
    float* __restrict__ hid, const unsigned short* __restrict__ Wtb,
    const float* __restrict__ g0, const float* __restrict__ be0,
    const float* __restrict__ b10, const float* __restrict__ b20,
    const float* __restrict__ g1, const float* __restrict__ be1,
    const float* __restrict__ b11, const float* __restrict__ b21,
    const float* __restrict__ hg, const float* __restrict__ hb,
    float* __restrict__ hh_out)
{
    __shared__ float sR[16][264];
    __shared__ unsigned short sA[16][264];
    const int tid = threadIdx.x;
    const int lane = tid & 63, wave = tid >> 6;
    const int l15 = lane & 15, hi = lane >> 4;
    const int cbase = wave * 64;
    const int row0 = blockIdx.x * 16;
    {   // load hid -> sR
        const int r = tid >> 4, cb = (tid & 15) * 4;
        #pragma unroll
        for (int q = 0; q < 4; ++q)
            *(float4*)&sR[r][cb + q*64] =
                *(const float4*)(hid + (size_t)(row0+r)*256 + cb + q*64);
    }
    __syncthreads();
    #pragma unroll
    for (int it = 0; it < 2; ++it){
        const float* g  = it ? g1  : g0;
        const float* be = it ? be1 : be0;
        const float* B1 = it ? b11 : b10;
        const float* B2 = it ? b21 : b20;
        const unsigned short* W1 = Wtb + (size_t)(it ? 2 : 0)*65536;
        const unsigned short* W2 = Wtb + (size_t)(it ? 3 : 1)*65536;
        {   // LN(sR) -> sA bf16; wave owns rows wave*4+j
            float4 gg = *(const float4*)(g + lane*4);
            float4 bb = *(const float4*)(be + lane*4);
            #pragma unroll
            for (int j = 0; j < 4; ++j){
                const int r = wave*4 + j;
                float4 v = *(const float4*)&sR[r][lane*4];
                float s = v.x+v.y+v.z+v.w;
                float q = v.x*v.x+v.y*v.y+v.z*v.z+v.w*v.w;
                #pragma unroll
                for (int m = 1; m < 64; m <<= 1){
                    s += __shfl_xor(s, m, 64); q += __shfl_xor(q, m, 64);
                }
                float mu = s*(1.f/256.f);
                float rs = rsqrtf(q*(1.f/256.f) - mu*mu + 1e-5f);
                ushort4 o;
                o.x = f2bf((v.x-mu)*rs*gg.x+bb.x);
                o.y = f2bf((v.y-mu)*rs*gg.y+bb.y);
                o.z = f2bf((v.z-mu)*rs*gg.z+bb.z);
                o.w = f2bf((v.w-mu)*rs*gg.w+bb.w);
                *(ushort4*)&sA[r][lane*4] = o;
            }
        }
        __syncthreads();
        {   // GEMM1 + gelu -> sA
            f32x4 acc[4];
            #pragma unroll
            for (int t = 0; t < 4; ++t){ acc[t][0]=0.f; acc[t][1]=0.f; acc[t][2]=0.f; acc[t][3]=0.f; }
            mfma_gemm16(sA, W1, l15, hi, cbase, acc);
            #pragma unroll
            for (int t = 0; t < 4; ++t){
                int ct = cbase + t*16 + l15;
                float bbx = B1[ct];
                #pragma unroll
                for (int j = 0; j < 4; ++j)
                    sA[hi*4 + j][ct] = f2bf(gelu_t(acc[t][j] + bbx));
            }
        }
        __syncthreads();
        {   // GEMM2 + bias + residual -> sR
            f32x4 acc[4];
            #pragma unroll
            for (int t = 0; t < 4; ++t){ acc[t][0]=0.f; acc[t][1]=0.f; acc[t][2]=0.f; acc[t][3]=0.f; }
            mfma_gemm16(sA, W2, l15, hi, cbase, acc);
            #pragma unroll
            for (int t = 0; t < 4; ++t){
                int ct = cbase + t*16 + l15;
                float bbx = B2[ct];
                #pragma unroll
                for (int j = 0; j < 4; ++j)
                    sR[hi*4 + j][ct] += acc[t][j] + bbx;
            }
        }
        __syncthreads();
    }
    {   // write hid back
        const int r = tid >> 4, cb = (tid & 15) * 4;
        #pragma unroll
        for (int q = 0; q < 4; ++q)
            *(float4*)(hid + (size_t)(row0+r)*256 + cb + q*64) =
                *(const float4*)&sR[r][cb + q*64];
    }
    {   // hh = LN(hid)*hg + hb (f32)
        float4 gg = *(const float4*)(hg + lane*4);
        float4 bb = *(const float4*)(hb + lane*4);
        #pragma unroll
        for (int j = 0; j < 4; ++j){
            const int r = wave*4 + j;
            float4 v = *(const float4*)&sR[r][lane*4];
            float s = v.x+v.y+v.z+v.w;
            float q = v.x*v.x+v.y*v.y+v.z*v.z+v.w*v.w;
            #pragma unroll
            for (int m = 1; m < 64; m <<= 1){
                s += __shfl_xor(s, m, 64); q += __shfl_xor(q, m, 64);
            }
            float mu = s*(1.f/256.f);
            float rs = rsqrtf(q*(1.f/256.f) - mu*mu + 1e-5f);
            float4 o = make_float4((v.x-mu)*rs*gg.x+bb.x, (v.y-mu)*rs*gg.y+bb.y,
                                   (v.z-mu)*rs*gg.z+bb.z, (v.w-mu)*rs*gg.w+bb.w);
            *(float4*)(hh_out + (size_t)(row0+r)*256 + lane*4) = o;
        }
    }
}

// rc = relu(Hn @ Hn^T), tiled GEMM. Grid (63, 4, batches_in_chunk).
__global__ __launch_bounds__(256) void k_corr(const float* __restrict__ HnTc,
                                              float* __restrict__ rcb)
{
    __shared__ float sA[64][32];
    __shared__ float sB[64][128];
    const int tid = threadIdx.x;
    const float* H = HnTc + (size_t)blockIdx.z * 64 * N;
    float* rc = rcb + (size_t)blockIdx.z * N * N;
    const int n0 = blockIdx.x * 32;
    const int cs = blockIdx.y * 512;
    const int ce = (cs + 512 < N) ? cs + 512 : N;
    #pragma unroll
    for (int j = 0; j < 8; ++j){
        int idx = tid + 256*j;
        int k = idx >> 5, r = idx & 31;
        int nn = n0 + r;
        sA[k][r] = (nn < N) ? H[(size_t)k*N + nn] : 0.f;
    }
    const int trow = tid >> 6;
    const int tcol = tid & 63;
    for (int mc = cs; mc < ce; mc += 128){
        __syncthreads();
        #pragma unroll
        for (int q = 0; q < 8; ++q){
            int f = tid + 256*q;
            int k = f >> 5, c4 = (f & 31) * 4;
            int m = mc + c4;
            float4 v = (m + 3 < N) ? *(const float4*)(H + (size_t)k*N + m)
                                   : make_float4(0.f,0.f,0.f,0.f);
            *(float4*)&sB[k][c4] = v;
        }
        __syncthreads();
        float acc[8][2];
        #pragma unroll
        for (int r = 0; r < 8; ++r){ acc[r][0] = 0.f; acc[r][1] = 0.f; }
        #pragma unroll 4
        for (int k = 0; k < 64; ++k){
            float2 b2v = *(const float2*)&sB[k][tcol*2];
            float4 a0 = *(const float4*)&sA[k][trow*8];
            float4 a1 = *(const float4*)&sA[k][trow*8 + 4];
            float av[8] = {a0.x,a0.y,a0.z,a0.w,a1.x,a1.y,a1.z,a1.w};
            #pragma unroll
            for (int r = 0; r < 8; ++r){
                acc[r][0] = fmaf(av[r], b2v.x, acc[r][0]);
                acc[r][1] = fmaf(av[r], b2v.y, acc[r][1]);
            }
        }
        int m = mc + tcol*2;
        if (m < N){
            #pragma unroll
            for (int r = 0; r < 8; ++r){
                int nn = n0 + trow*8 + r;
                if (nn < N){
                    float2 o = make_float2(fmaxf(acc[r][0],0.f), fmaxf(acc[r][1],0.f));
                    *(float2*)(rc + (size_t)nn*N + m) = o;
                }
            }
        }
    }
}

// Per-row selection (softmax + 2x top-20) and sparse aggregation.
// ONE ROW PER WAVE, 4 rows per block. Zn is staged in LDS in 8 chunks of
// 256 rows (4 SoA float4 planes) shared by all 4 waves -> 4x less L1
// traffic (the measured bottleneck). All barriers uniform. Candidate
// mapping m = (i>>2)*256 + lane + 64*(i&3); arrays statically indexed.
__global__ __launch_bounds__(256) void k_select(
    const float* __restrict__ rcb, const float* __restrict__ Zn,
    const float* __restrict__ hh, const float* __restrict__ mix_logit,
    float* __restrict__ msg, int row_base)
{
    __shared__ float4 zq[4][256];
    __shared__ float cl[4][128];
    __shared__ int   lm[4][64];
    __shared__ float lv[4][64];
    const int tid = threadIdx.x;
    const int lane = tid & 63, wv = tid >> 6;
    const int rloc = blockIdx.x * 4 + wv;   // row within this rc chunk
    const int n = row_base + rloc;          // global row
    const int base = (n / N) * N;
    const float* rcrow = rcb + (size_t)rloc * N;
    float* clw = cl[wv];
    float zr[16];
    {   // own row's Zn (wave-uniform)
        const float4* zp = (const float4*)(Zn + (size_t)n * 16);
        float4 z0 = zp[0], z1 = zp[1], z2 = zp[2], z3 = zp[3];
        zr[0]=z0.x; zr[1]=z0.y; zr[2]=z0.z; zr[3]=z0.w;
        zr[4]=z1.x; zr[5]=z1.y; zr[6]=z1.z; zr[7]=z1.w;
        zr[8]=z2.x; zr[9]=z2.y; zr[10]=z2.z; zr[11]=z2.w;
        zr[12]=z3.x; zr[13]=z3.y; zr[14]=z3.z; zr[15]=z3.w;
    }
    float e_[32], rc_[32];
    float sumE = 0.f, sumC = 0.f;
    #pragma unroll
    for (int c = 0; c < 8; ++c){
        if (c > 0) __syncthreads();     // uniform: previous chunk fully read
        {   // stage 256 Zn rows into 4 SoA planes (cooperative, coalesced)
            #pragma unroll
            for (int k = 0; k < 4; ++k){
                int idx = tid + k*256;          // 0..1023
                int ml = idx >> 2, q = idx & 3;
                int m = c*256 + ml;
                float4 v = make_float4(0.f,0.f,0.f,0.f);
                if (m < N) v = *(const float4*)(Zn + (size_t)(base + m)*16 + q*4);
                zq[q][ml] = v;
            }
        }
        __syncthreads();                // uniform: staging visible
        #pragma unroll
        for (int j = 0; j < 4; ++j){
            const int i = c*4 + j;
            const int ml = lane + 64*j;
            const int m = c*256 + ml;
            float rcv = -1.f, e = 0.f;
            if (m < N){
                rcv = rcrow[m];
                float4 za = zq[0][ml], zb = zq[1][ml], zc = zq[2][ml], zd = zq[3][ml];
                float s = za.x * zr[0];
                s = fmaf(za.y, zr[1], s);  s = fmaf(za.z, zr[2], s);  s = fmaf(za.w, zr[3], s);
                s = fmaf(zb.x, zr[4], s);  s = fmaf(zb.y, zr[5], s);  s = fmaf(zb.z, zr[6], s);
                s = fmaf(zb.w, zr[7], s);  s = fmaf(zc.x, zr[8], s);  s = fmaf(zc.y, zr[9], s);
                s = fmaf(zc.z, zr[10], s); s = fmaf(zc.w, zr[11], s); s = fmaf(zd.x, zr[12], s);
                s = fmaf(zd.y, zr[13], s); s = fmaf(zd.z, zr[14], s); s = fmaf(zd.w, zr[15], s);
                e = __expf(s);          // |s| <= 1, safe without max-subtraction
                sumE += e; sumC += rcv;
            }
            e_[i] = e; rc_[i] = rcv;
        }
    }
    __syncthreads();                    // uniform: zq no longer needed
    #pragma unroll
    for (int mm = 1; mm < 64; mm <<= 1){
        sumE += __shfl_xor(sumE, mm, 64);
        sumC += __shfl_xor(sumC, mm, 64);
    }
    float c_kth = wave_topk20_sync(rc_, clw);
    float skl = 0.f;
    #pragma unroll
    for (int i = 0; i < 32; ++i){ if (rc_[i] >= c_kth) skl += rc_[i]; }
    #pragma unroll
    for (int mm = 1; mm < 64; mm <<= 1) skl += __shfl_xor(skl, mm, 64);
    const float invSumExp = 1.f / sumE;
    const float r1 = 1.f / (sumC + EPSF);
    const float rollsc = r1 * (1.f / (skl * r1 + EPSF));
    const float mixw = 1.f / (1.f + __expf(-mix_logit[0]));
    const float onemix = 1.f - mixw;
    float sumAm = 0.f;
    #pragma unroll
    for (int i = 0; i < 32; ++i){       // e_ becomes am in place
        float am = -1.f;
        if (rc_[i] >= 0.f){
            float afdg  = e_[i] * invSumExp;
            float aroll = (rc_[i] >= c_kth) ? rc_[i] * rollsc : 0.f;
            am = fmaf(mixw, afdg, onemix * aroll);
            sumAm += am;
        }
        e_[i] = am;
    }
    #pragma unroll
    for (int mm = 1; mm < 64; mm <<= 1) sumAm += __shfl_xor(sumAm, mm, 64);
    float am_kth = wave_topk20_sync(e_, clw);
    float sk2 = 0.f;
    #pragma unroll
    for (int i = 0; i < 32; ++i){ if (e_[i] >= am_kth) sk2 += e_[i]; }
    #pragma unroll
    for (int mm = 1; mm < 64; mm <<= 1) sk2 += __shfl_xor(sk2, mm, 64);
    const float ra = 1.f / (sumAm + EPSF);
    const float fsc = ra * (1.f / (sk2 * ra + EPSF));
    // deterministic compaction of kept entries into this wave's list
    unsigned keep = 0; int cnt = 0;
    #pragma unroll
    for (int i = 0; i < 32; ++i){
        bool kp = (e_[i] >= am_kth) && (e_[i] > 0.f);
        if (kp){ keep |= (1u << i); cnt++; }
    }
    int incl = cnt;
    #pragma unroll
    for (int s = 1; s < 64; s <<= 1){
        int o = __shfl_up(incl, s, 64);
        if (lane >= s) incl += o;
    }
    int total = __shfl(incl, 63, 64);
    if (total > 64) total = 64;
    int offs = incl - cnt;
    #pragma unroll
    for (int i = 0; i < 32; ++i){
        if (keep & (1u << i)){
            if (offs < 64){
                lm[wv][offs] = (i >> 2)*256 + lane + 64*(i & 3);
                lv[wv][offs] = e_[i] * fsc;
            }
            offs++;
        }
    }
    __syncthreads();                    // uniform: fences lm/lv writes
    // msg[n, lane*4 .. +3] = sum_kept w * hh[m, :]
    float a0 = 0.f, a1 = 0.f, a2 = 0.f, a3 = 0.f;
    for (int i = 0; i < total; ++i){
        float w = lv[wv][i];
        const float4 hv = *(const float4*)(hh + ((size_t)(base + lm[wv][i]))*256 + lane*4);
        a0 = fmaf(w, hv.x, a0); a1 = fmaf(w, hv.y, a1);
        a2 = fmaf(w, hv.z, a2); a3 = fmaf(w, hv.w, a3);
    }
    *(float4*)(msg + (size_t)n*256 + lane*4) = make_float4(a0, a1, a2, a3);
}

// Graph-residual MLP + head. MFMA bf16. 16 rows/block, 500 blocks.
__global__ __launch_bounds__(256) void k_gblk(
    const float* __restrict__ hid, const float* __restrict__ msgb,
    const unsigned short* __restrict__ Wtb,
    const float* __restrict__ b1, const float* __restrict__ b2,
    const float* __restrict__ hg, const float* __restrict__ hb,
    const float* __restrict__ hw, const float* __restrict__ hbias,
    float* __restrict__ y)
{
    __shared__ float sR[16][264];
    __shared__ unsigned short sA[16][264];
    const int tid = threadIdx.x;
    const int lane = tid & 63, wave = tid >> 6;
    const int l15 = lane & 15, hi = lane >> 4;
    const int cbase = wave * 64;
    const int row0 = blockIdx.x * 16;
    {   // hid -> sR (f32), msg -> sA (bf16)
        const int r = tid >> 4, cb = (tid & 15) * 4;
        #pragma unroll
        for (int q = 0; q < 4; ++q){
            *(float4*)&sR[r][cb + q*64] =
                *(const float4*)(hid + (size_t)(row0+r)*256 + cb + q*64);
            float4 mv = *(const float4*)(msgb + (size_t)(row0+r)*256 + cb + q*64);
            ushort4 u;
            u.x = f2bf(mv.x); u.y = f2bf(mv.y); u.z = f2bf(mv.z); u.w = f2bf(mv.w);
            *(ushort4*)&sA[r][cb + q*64] = u;
        }
    }
    __syncthreads();
    {   // GEMM1 + gelu -> sA
        f32x4 acc[4];
        #pragma unroll
        for (int t = 0; t < 4; ++t){ acc[t][0]=0.f; acc[t][1]=0.f; acc[t][2]=0.f; acc[t][3]=0.f; }
        mfma_gemm16(sA, Wtb + (size_t)4*65536, l15, hi, cbase, acc);
        #pragma unroll
        for (int t = 0; t < 4; ++t){
            int ct = cbase + t*16 + l15;
            float bbx = b1[ct];
            #pragma unroll
            for (int j = 0; j < 4; ++j)
                sA[hi*4 + j][ct] = f2bf(gelu_t(acc[t][j] + bbx));
        }
    }
    __syncthreads();
    {   // GEMM2 + bias + residual -> sR
        f32x4 acc[4];
        #pragma unroll
        for (int t = 0; t < 4; ++t){ acc[t][0]=0.f; acc[t][1]=0.f; acc[t][2]=0.f; acc[t][3]=0.f; }
        mfma_gemm16(sA, Wtb + (size_t)5*65536, l15, hi, cbase, acc);
        #pragma unroll
        for (int t = 0; t < 4; ++t){
            int ct = cbase + t*16 + l15;
            float bbx = b2[ct];
            #pragma unroll
            for (int j = 0; j < 4; ++j)
                sR[hi*4 + j][ct] += acc[t][j] + bbx;
        }
    }
    __syncthreads();
    {   // head: y = gelu(LN(sR)) @ head_w + head_b; wave owns rows wave*4+j
        float4 gg = *(const float4*)(hg + lane*4);
        float4 bb = *(const float4*)(hb + lane*4);
        float4 wv = *(const float4*)(hw + lane*4);
        #pragma unroll
        for (int j = 0; j < 4; ++j){
            const int r = wave*4 + j;
            float4 v = *(const float4*)&sR[r][lane*4];
            float s = v.x+v.y+v.z+v.w;
            float q = v.x*v.x+v.y*v.y+v.z*v.z+v.w*v.w;
            #pragma unroll
            for (int m = 1; m < 64; m <<= 1){
                s += __shfl_xor(s, m, 64); q += __shfl_xor(q, m, 64);
            }
            float mu = s*(1.f/256.f);
            float rs = rsqrtf(q*(1.f/256.f) - mu*mu + 1e-5f);
            float p = gelu_t((v.x-mu)*rs*gg.x+bb.x)*wv.x
                    + gelu_t((v.y-mu)*rs*gg.y+bb.y)*wv.y
                    + gelu_t((v.z-mu)*rs*gg.z+bb.z)*wv.z
                    + gelu_t((v.w-mu)*rs*gg.w+bb.w)*wv.w;
            #pragma unroll
            for (int m = 1; m < 64; m <<= 1) p += __shfl_xor(p, m, 64);
            if (lane == 0) y[row0 + r] = p + hbias[0];
        }
    }
}

// ---------------- launch ----------------

extern "C" void kernel_launch(void* const* d_in, const int* in_sizes, int n_in,
                              void* d_out, int out_size, void* d_ws, size_t ws_size,
                              hipStream_t stream)
{
    (void)in_sizes; (void)n_in; (void)out_size;
    const float* X         = (const float*)d_in[0];
    const float* history   = (const float*)d_in[2];
    const float* enc_ln_g  = (const float*)d_in[3];
    const float* enc_ln_b  = (const float*)d_in[4];
    const float* enc_w1    = (const float*)d_in[5];
    const float* enc_b1    = (const float*)d_in[6];
    const float* enc_w2    = (const float*)d_in[7];
    const float* enc_b2    = (const float*)d_in[8];
    const float* proj_w    = (const float*)d_in[9];
    const float* proj_b    = (const float*)d_in[10];
    const float* fdg_B     = (const float*)d_in[11];
    const float* mixlog    = (const float*)d_in[12];
    const float* gblk_ln_g = (const float*)d_in[13];
    const float* gblk_ln_b = (const float*)d_in[14];
    const float* gblk_w1   = (const float*)d_in[15];
    const float* gblk_b1   = (const float*)d_in[16];
    const float* gblk_w2   = (const float*)d_in[17];
    const float* gblk_b2   = (const float*)d_in[18];
    const float* head_ln_g = (const float*)d_in[19];
    const float* head_ln_b = (const float*)d_in[20];
    const float* head_w    = (const float*)d_in[21];
    const float* head_b    = (const float*)d_in[22];

    float* ws  = (float*)d_ws;
    float* hid = ws;                              // 2,048,000 f
    float* hh  = hid + (size_t)NROWS*DH;          // 2,048,000 f
    float* msg = hh  + (size_t)NROWS*DH;          // 2,048,000 f
    float* Znb = msg + (size_t)NROWS*DH;          //   128,000 f
    float* HnT = Znb + (size_t)NROWS*16;          //   512,000 f
    unsigned short* Wtb = (unsigned short*)(HnT + (size_t)NB*64*N);  // 6*65536 us
    float* rcbuf = (float*)(Wtb + (size_t)6*65536);
    float* y   = (float*)d_out;

    const size_t baseF = (size_t)3*NROWS*DH + (size_t)NROWS*16 + (size_t)NB*64*N
                       + (size_t)6*65536/2;
    const size_t perBatchF = (size_t)N*N;
    size_t availF = (ws_size/4 > baseF) ? (ws_size/4 - baseF) : perBatchF;
    int bpc = (availF >= 4*perBatchF) ? 4 : (availF >= 2*perBatchF) ? 2 : 1;

    k_wcvt<<<dim3(8,8,6), 256, 0, stream>>>(
        (const float*)d_in[25], (const float*)d_in[27],
        (const float*)d_in[31], (const float*)d_in[33],
        gblk_w1, gblk_w2, Wtb);
    k_enc<<<NROWS/8, 256, 0, stream>>>(X, enc_ln_g, enc_ln_b, enc_w1, enc_b1, enc_w2, enc_b2,
                                       proj_w, proj_b, fdg_B, hid, Znb);
    k_hist<<<NROWS/4, 256, 0, stream>>>(history, HnT);
    k_mlp2<<<NROWS/16, 256, 0, stream>>>(hid, Wtb,
        (const float*)d_in[23], (const float*)d_in[24],
        (const float*)d_in[26], (const float*)d_in[28],
        (const float*)d_in[29], (const float*)d_in[30],
        (const float*)d_in[32], (const float*)d_in[34],
        gblk_ln_g, gblk_ln_b, hh);
    for (int cb = 0; cb < NB; cb += bpc){
        dim3 g1(63, 4, bpc);
        k_corr<<<g1, 256, 0, stream>>>(HnT + (size_t)cb*64*N, rcbuf);
        k_select<<<bpc*N/4, 256, 0, stream>>>(rcbuf, Znb, hh, mixlog, msg, cb*N);
    }
    k_gblk<<<NROWS/16, 256, 0, stream>>>(hid, msg, Wtb, gblk_b1, gblk_b2,
                                         head_ln_g, head_ln_b, head_w, head_b, y);
}

// Round 15
// 234.213 us; speedup vs baseline: 1.6305x; 1.0072x over previous
//
#include <hip/hip_runtime.h>
#include <math.h>

#define NB 4
#define N 2000
#define DIN 128
#define DH 256
#define NROWS (NB*N)          // 8000
#define EPSF 1e-8f

typedef __attribute__((ext_vector_type(8))) short bf16x8;
typedef __attribute__((ext_vector_type(4))) float f32x4;

// ---------------- helpers ----------------

__device__ __forceinline__ float gelu_t(float x){
    // jax.nn.gelu approximate=True (tanh form)
    float z = 0.7978845608028654f * fmaf(0.044715f * x * x, x, x);
    z = fminf(fmaxf(z, -20.f), 20.f);
    float e = __expf(2.f * z);
    return 0.5f * x * (1.f + (e - 1.f) / (e + 1.f));
}

__device__ __forceinline__ unsigned short f2bf(float f){   // RNE f32->bf16 bits
    unsigned u = __float_as_uint(f);
    return (unsigned short)((u + 0x7FFFu + ((u >> 16) & 1u)) >> 16);
}

// full descending bitonic sort of 64 values across a wave (lane 0 = largest)
__device__ __forceinline__ float wave_sort64_desc(float v){
    const int lane = threadIdx.x & 63;
    #pragma unroll
    for (int k = 2; k <= 64; k <<= 1){
        #pragma unroll
        for (int j = k >> 1; j >= 1; j >>= 1){
            float o = __shfl_xor(v, j, 64);
            bool keepMax = ((lane & k) == 0) == ((lane & j) == 0);
            v = keepMax ? fmaxf(v, o) : fminf(v, o);
        }
    }
    return v;
}

// descending bitonic sort of 128 values (2 regs/lane; element idx = 2*lane+r)
__device__ __forceinline__ void sort128_desc(float &v0, float &v1){
    const int lane = threadIdx.x & 63;
    #pragma unroll
    for (int k = 2; k <= 128; k <<= 1){
        #pragma unroll
        for (int j = k >> 1; j >= 2; j >>= 1){
            int lj = j >> 1;
            float o0 = __shfl_xor(v0, lj, 64);
            float o1 = __shfl_xor(v1, lj, 64);
            int idx0 = 2*lane, idx1 = 2*lane + 1;
            bool km0 = ((idx0 & k) == 0) == ((idx0 & j) == 0);
            bool km1 = ((idx1 & k) == 0) == ((idx1 & j) == 0);
            v0 = km0 ? fmaxf(v0, o0) : fminf(v0, o0);
            v1 = km1 ? fmaxf(v1, o1) : fminf(v1, o1);
        }
        {   // j == 1: within-lane CAS
            bool up = (((2*lane) & k) == 0);
            float a = fmaxf(v0, v1), b = fminf(v0, v1);
            v0 = up ? a : b;
            v1 = up ? b : a;
        }
    }
}

// Non-destructive wave-local exact 20th-largest (with multiplicity) fallback:
// descending distinct-value extraction; <=20 iterations; register-only.
__device__ __forceinline__ float wave_topk20_slow32(const float (&v)[32]){
    float cur = 1e30f, kth = 0.f;
    int consumed = 0;
    for (int it = 0; it < 20; ++it){
        if (consumed >= 20) break;
        float bm = -3.f;
        #pragma unroll
        for (int i = 0; i < 32; ++i){ if (v[i] < cur) bm = fmaxf(bm, v[i]); }
        #pragma unroll
        for (int mm = 1; mm < 64; mm <<= 1) bm = fmaxf(bm, __shfl_xor(bm, mm, 64));
        int c = 0;
        #pragma unroll
        for (int i = 0; i < 32; ++i) c += (v[i] == bm) ? 1 : 0;
        #pragma unroll
        for (int mm = 1; mm < 64; mm <<= 1) c += __shfl_xor(c, mm, 64);
        consumed += c;
        kth = bm;
        cur = bm;
    }
    return kth;
}

// Exact wave-local 20th-largest (with multiplicity) of 64 lanes x 32 regs.
// cl: this wave's private 128-float LDS region. MUST be called by ALL
// threads of the block at the same program point: the two __syncthreads()
// are uniform (outside any divergent branch). Three paths by candidate
// count (wave-uniform choice): <=64 -> 21-stage sort64 (expected case,
// E[total]~22), <=128 -> sort128, else register fallback.
__device__ __forceinline__ float wave_topk20_sync(const float (&v)[32], float* cl){
    const int lane = threadIdx.x & 63;
    float mx = v[0];
    #pragma unroll
    for (int i = 1; i < 32; ++i) mx = fmaxf(mx, v[i]);
    float sm = wave_sort64_desc(mx);
    float u = __shfl(sm, 19, 64);       // 20th-largest lane-max: u <= true kth
    int cnt = 0;
    #pragma unroll
    for (int i = 0; i < 32; ++i) cnt += (v[i] >= u) ? 1 : 0;
    int incl = cnt;
    #pragma unroll
    for (int s = 1; s < 64; s <<= 1){
        int o = __shfl_up(incl, s, 64);
        if (lane >= s) incl += o;
    }
    const int total = __shfl(incl, 63, 64);   // >= 20 by construction of u
    const bool fast = (total <= 128);   // wave-uniform
    if (fast){
        int offs = incl - cnt;
        #pragma unroll
        for (int i = 0; i < 32; ++i){
            if (v[i] >= u) cl[offs++] = v[i];
        }
    }
    __syncthreads();                    // uniform: fences candidate writes
    float kth;
    if (total <= 64){                   // short path: single-reg bitonic sort
        float c0 = (lane < total) ? cl[lane] : -3.f;
        c0 = wave_sort64_desc(c0);
        kth = __shfl(c0, 19, 64);       // element index 19
    } else if (fast){
        float c0 = (2*lane     < total) ? cl[2*lane]     : -3.f;
        float c1 = (2*lane + 1 < total) ? cl[2*lane + 1] : -3.f;
        sort128_desc(c0, c1);
        kth = __shfl(c1, 9, 64);        // element index 19
    } else {
        kth = wave_topk20_slow32(v);
    }
    __syncthreads();                    // uniform: cl safe to reuse after return
    return kth;
}

// Per-wave MFMA GEMM: out16x64 = A(16x256, bf16 LDS) @ Wt-slice.
// Wt is [col][k] bf16. Wave covers cols cbase..cbase+63 as 4 16-col tiles.
// Internal barrier after A-frag loads => caller may overwrite sA after return.
__device__ __forceinline__ void mfma_gemm16(
    const unsigned short (*__restrict__ sA)[264], const unsigned short* __restrict__ Wt,
    int l15, int hi, int cbase, f32x4 acc[4])
{
    bf16x8 a[8];
    #pragma unroll
    for (int kb = 0; kb < 8; ++kb)
        a[kb] = *(const bf16x8*)&sA[l15][kb*32 + hi*8];
    __syncthreads();                     // all waves' A-frags in regs
    const unsigned short* wp0 = Wt + (size_t)(cbase      + l15)*256 + hi*8;
    const unsigned short* wp1 = Wt + (size_t)(cbase + 16 + l15)*256 + hi*8;
    const unsigned short* wp2 = Wt + (size_t)(cbase + 32 + l15)*256 + hi*8;
    const unsigned short* wp3 = Wt + (size_t)(cbase + 48 + l15)*256 + hi*8;
    #pragma unroll
    for (int kb = 0; kb < 8; ++kb){
        bf16x8 b0 = *(const bf16x8*)(wp0 + kb*32);
        bf16x8 b1 = *(const bf16x8*)(wp1 + kb*32);
        bf16x8 b2 = *(const bf16x8*)(wp2 + kb*32);
        bf16x8 b3 = *(const bf16x8*)(wp3 + kb*32);
        acc[0] = __builtin_amdgcn_mfma_f32_16x16x32_bf16(a[kb], b0, acc[0], 0, 0, 0);
        acc[1] = __builtin_amdgcn_mfma_f32_16x16x32_bf16(a[kb], b1, acc[1], 0, 0, 0);
        acc[2] = __builtin_amdgcn_mfma_f32_16x16x32_bf16(a[kb], b2, acc[2], 0, 0, 0);
        acc[3] = __builtin_amdgcn_mfma_f32_16x16x32_bf16(a[kb], b3, acc[3], 0, 0, 0);
    }
}

// ---------------- kernels ----------------

// Weight prep: Wt[m][c][k] = bf16(W[m][k][c]), 6 matrices 256x256. Grid (8,8,6).
__global__ __launch_bounds__(256) void k_wcvt(
    const float* __restrict__ w10, const float* __restrict__ w20,
    const float* __restrict__ w11, const float* __restrict__ w21,
    const float* __restrict__ gw1, const float* __restrict__ gw2,
    unsigned short* __restrict__ Wt)
{
    __shared__ float t[32][33];
    const int m = blockIdx.z;
    const float* W = (m==0)?w10:(m==1)?w20:(m==2)?w11:(m==3)?w21:(m==4)?gw1:gw2;
    unsigned short* out = Wt + (size_t)m*65536;
    const int k0 = blockIdx.y*32, c0 = blockIdx.x*32;
    const int tx = threadIdx.x & 31, ty = threadIdx.x >> 5;
    #pragma unroll
    for (int j = 0; j < 4; ++j){
        int k = ty*4 + j;
        t[k][tx] = W[(size_t)(k0+k)*256 + c0+tx];
    }
    __syncthreads();
    #pragma unroll
    for (int j = 0; j < 4; ++j){
        int c = ty*4 + j;
        out[(size_t)(c0+c)*256 + k0+tx] = f2bf(t[tx][c]);
    }
}

// Encoder bottleneck + projection + FDG embedding. 8 rows/block, 1000 blocks.
__global__ __launch_bounds__(256) void k_enc(
    const float* __restrict__ X,
    const float* __restrict__ lg, const float* __restrict__ lb,
    const float* __restrict__ w1, const float* __restrict__ b1,
    const float* __restrict__ w2, const float* __restrict__ b2,
    const float* __restrict__ pw, const float* __restrict__ pb,
    const float* __restrict__ fB,
    float* __restrict__ hid, float* __restrict__ Zn)
{
    __shared__ float sH[8][132];
    __shared__ float sT[8][68];
    __shared__ float sXm[8][132];
    const int tid = threadIdx.x;
    const int lane = tid & 63;
    const int wave = tid >> 6;
    const int rg = wave * 2;
    const int row0 = blockIdx.x * 8;
    const int cx = lane * 2;
    float2 x0 = *(const float2*)(X + (size_t)(row0+rg  )*128 + cx);
    float2 x1 = *(const float2*)(X + (size_t)(row0+rg+1)*128 + cx);
    {   // LN over 128 (two rows per wave, full-wave reduce)
        float sa = x0.x + x0.y, sb = x1.x + x1.y;
        float qa = x0.x*x0.x + x0.y*x0.y, qb = x1.x*x1.x + x1.y*x1.y;
        #pragma unroll
        for (int m = 1; m < 64; m <<= 1){
            sa += __shfl_xor(sa, m, 64); sb += __shfl_xor(sb, m, 64);
            qa += __shfl_xor(qa, m, 64); qb += __shfl_xor(qb, m, 64);
        }
        float mua = sa*(1.f/128.f), mub = sb*(1.f/128.f);
        float rsa = rsqrtf(qa*(1.f/128.f) - mua*mua + 1e-5f);
        float rsb = rsqrtf(qb*(1.f/128.f) - mub*mub + 1e-5f);
        float2 gg = *(const float2*)(lg + cx);
        float2 bb = *(const float2*)(lb + cx);
        sH[rg  ][cx] = (x0.x - mua)*rsa*gg.x + bb.x;
        sH[rg  ][cx+1] = (x0.y - mua)*rsa*gg.y + bb.y;
        sH[rg+1][cx] = (x1.x - mub)*rsb*gg.x + bb.x;
        sH[rg+1][cx+1] = (x1.y - mub)*rsb*gg.y + bb.y;
    }
    __syncthreads();
    {   // GEMM1 (128->64): one col per lane, two rows
        float a0 = 0.f, a1 = 0.f;
        #pragma unroll 4
        for (int k = 0; k < 128; ++k){
            float h0 = sH[rg][k], h1 = sH[rg+1][k];
            float wk = w1[k*64 + lane];
            a0 = fmaf(h0, wk, a0);
            a1 = fmaf(h1, wk, a1);
        }
        float bb = b1[lane];
        sT[rg  ][lane] = gelu_t(a0 + bb);
        sT[rg+1][lane] = gelu_t(a1 + bb);
    }
    __syncthreads();
    {   // GEMM2 (64->128): Xm = X + t@w2 + b2 -> sXm
        float p0x=0.f,p0y=0.f,p1x=0.f,p1y=0.f;
        #pragma unroll 4
        for (int k = 0; k < 64; ++k){
            float t0 = sT[rg][k], t1 = sT[rg+1][k];
            float2 w = *(const float2*)(w2 + k*128 + cx);
            p0x = fmaf(t0, w.x, p0x); p0y = fmaf(t0, w.y, p0y);
            p1x = fmaf(t1, w.x, p1x); p1y = fmaf(t1, w.y, p1y);
        }
        float2 bb = *(const float2*)(b2 + cx);
        sXm[rg  ][cx]   = x0.x + p0x + bb.x;
        sXm[rg  ][cx+1] = x0.y + p0y + bb.y;
        sXm[rg+1][cx]   = x1.x + p1x + bb.x;
        sXm[rg+1][cx+1] = x1.y + p1y + bb.y;
    }
    __syncthreads();
    {   // GEMM3: hid = Xm @ proj_w + proj_b, col-split per wave (64 cols each)
        const int ri = lane >> 4;
        const int wc = wave*64 + (lane & 15)*4;
        float a0[4] = {0,0,0,0}, a1[4] = {0,0,0,0};
        #pragma unroll 4
        for (int k = 0; k < 128; ++k){
            float h0 = sXm[ri*2][k], h1 = sXm[ri*2+1][k];
            float4 w = *(const float4*)(pw + k*256 + wc);
            a0[0]=fmaf(h0,w.x,a0[0]); a0[1]=fmaf(h0,w.y,a0[1]); a0[2]=fmaf(h0,w.z,a0[2]); a0[3]=fmaf(h0,w.w,a0[3]);
            a1[0]=fmaf(h1,w.x,a1[0]); a1[1]=fmaf(h1,w.y,a1[1]); a1[2]=fmaf(h1,w.z,a1[2]); a1[3]=fmaf(h1,w.w,a1[3]);
        }
        float4 bb = *(const float4*)(pb + wc);
        float4 o0 = make_float4(a0[0]+bb.x, a0[1]+bb.y, a0[2]+bb.z, a0[3]+bb.w);
        float4 o1 = make_float4(a1[0]+bb.x, a1[1]+bb.y, a1[2]+bb.z, a1[3]+bb.w);
        *(float4*)(hid + (size_t)(row0+ri*2  )*256 + wc) = o0;
        *(float4*)(hid + (size_t)(row0+ri*2+1)*256 + wc) = o1;
    }
    if (tid < 128){   // Z = Xm @ fdg_B^T ; Zn = Z/(||Z||+eps)
        const int r = tid >> 4, q = tid & 15;
        float z = 0.f;
        #pragma unroll 4
        for (int k = 0; k < 128; ++k) z = fmaf(sXm[r][k], fB[q*128 + k], z);
        float s2 = z*z;
        #pragma unroll
        for (int m = 1; m < 16; m <<= 1) s2 += __shfl_xor(s2, m, 64);
        Zn[(size_t)(row0 + r)*16 + q] = z / (sqrtf(s2) + EPSF);
    }
}

// history -> normalized (pre-scaled by 1/8), stored TRANSPOSED: HnT[b][t][n]
__global__ __launch_bounds__(256) void k_hist(const float* __restrict__ H, float* __restrict__ HnT)
{
    const int row  = blockIdx.x * 4 + (threadIdx.x >> 6);
    const int lane = threadIdx.x & 63;
    float v = H[(size_t)row*64 + lane];
    float s = v;
    #pragma unroll
    for (int mm = 1; mm < 64; mm <<= 1) s += __shfl_xor(s, mm, 64);
    float mu = s * (1.f/64.f);
    float d = v - mu;
    float s2 = d*d;
    #pragma unroll
    for (int mm = 1; mm < 64; mm <<= 1) s2 += __shfl_xor(s2, mm, 64);
    float sd = sqrtf(s2 * (1.f/64.f));
    const int b = row / N, nloc = row % N;
    HnT[(size_t)b*64*N + (size_t)lane*N + nloc] = d / ((sd + EPSF) * 8.f);
}

// Fused residual MLP blocks 0+1 + gblk-LN (hh). MFMA bf16. 16 rows/block.
__global__ __launch_bounds__(256) void k_mlp2(
    float* __restrict__ hid, const unsigned short* __restrict__ Wtb,
    const float* __restrict__ g0, const float* __restrict__ be0,
    const float* __restrict__ b10, const float* __restrict__ b20,
    const float* __restrict__ g1, const float* __restrict__ be1,
    const float* __restrict__ b11, const float* __restrict__ b21,
    const float* __restrict__ hg, const float* __restrict__ hb,
    float* __restrict__ hh_out)
{
    __shared__ float sR[16][264];
    __shared__ unsigned short sA[16][264];
    const int tid = threadIdx.x;
    const int lane = tid & 63, wave = tid >> 6;
    const int l15 = lane & 15, hi = lane >> 4;
    const int cbase = wave * 64;
    const int row0 = blockIdx.x * 16;
    {   // load hid -> sR
        const int r = tid >> 4, cb = (tid & 15) * 4;
        #pragma unroll
        for (int q = 0; q < 4; ++q)
            *(float4*)&sR[r][cb + q*64] =
                *(const float4*)(hid + (size_t)(row0+r)*256 + cb + q*64);
    }
    __syncthreads();
    #pragma unroll
    for (int it = 0; it < 2; ++it){
        const float* g  = it ? g1  : g0;
        const float* be = it ? be1 : be0;
        const float* B1 = it ? b11 : b10;
        const float* B2 = it ? b21 : b20;
        const unsigned short* W1 = Wtb + (size_t)(it ? 2 : 0)*65536;
        const unsigned short* W2 = Wtb + (size_t)(it ? 3 : 1)*65536;
        {   // LN(sR) -> sA bf16; wave owns rows wave*4+j
            float4 gg = *(const float4*)(g + lane*4);
            float4 bb = *(const float4*)(be + lane*4);
            #pragma unroll
            for (int j = 0; j < 4; ++j){
                const int r = wave*4 + j;
                float4 v = *(const float4*)&sR[r][lane*4];
                float s = v.x+v.y+v.z+v.w;
                float q = v.x*v.x+v.y*v.y+v.z*v.z+v.w*v.w;
                #pragma unroll
                for (int m = 1; m < 64; m <<= 1){
                    s += __shfl_xor(s, m, 64); q += __shfl_xor(q, m, 64);
                }
                float mu = s*(1.f/256.f);
                float rs = rsqrtf(q*(1.f/256.f) - mu*mu + 1e-5f);
                ushort4 o;
                o.x = f2bf((v.x-mu)*rs*gg.x+bb.x);
                o.y = f2bf((v.y-mu)*rs*gg.y+bb.y);
                o.z = f2bf((v.z-mu)*rs*gg.z+bb.z);
                o.w = f2bf((v.w-mu)*rs*gg.w+bb.w);
                *(ushort4*)&sA[r][lane*4] = o;
            }
        }
        __syncthreads();
        {   // GEMM1 + gelu -> sA
            f32x4 acc[4];
            #pragma unroll
            for (int t = 0; t < 4; ++t){ acc[t][0]=0.f; acc[t][1]=0.f; acc[t][2]=0.f; acc[t][3]=0.f; }
            mfma_gemm16(sA, W1, l15, hi, cbase, acc);
            #pragma unroll
            for (int t = 0; t < 4; ++t){
                int ct = cbase + t*16 + l15;
                float bbx = B1[ct];
                #pragma unroll
                for (int j = 0; j < 4; ++j)
                    sA[hi*4 + j][ct] = f2bf(gelu_t(acc[t][j] + bbx));
            }
        }
        __syncthreads();
        {   // GEMM2 + bias + residual -> sR
            f32x4 acc[4];
            #pragma unroll
            for (int t = 0; t < 4; ++t){ acc[t][0]=0.f; acc[t][1]=0.f; acc[t][2]=0.f; acc[t][3]=0.f; }
            mfma_gemm16(sA, W2, l15, hi, cbase, acc);
            #pragma unroll
            for (int t = 0; t < 4; ++t){
                int ct = cbase + t*16 + l15;
                float bbx = B2[ct];
                #pragma unroll
                for (int j = 0; j < 4; ++j)
                    sR[hi*4 + j][ct] += acc[t][j] + bbx;
            }
        }
        __syncthreads();
    }
    {   // write hid back
        const int r = tid >> 4, cb = (tid & 15) * 4;
        #pragma unroll
        for (int q = 0; q < 4; ++q)
            *(float4*)(hid + (size_t)(row0+r)*256 + cb + q*64) =
                *(const float4*)&sR[r][cb + q*64];
    }
    {   // hh = LN(hid)*hg + hb (f32)
        float4 gg = *(const float4*)(hg + lane*4);
        float4 bb = *(const float4*)(hb + lane*4);
        #pragma unroll
        for (int j = 0; j < 4; ++j){
            const int r = wave*4 + j;
            float4 v = *(const float4*)&sR[r][lane*4];
            float s = v.x+v.y+v.z+v.w;
            float q = v.x*v.x+v.y*v.y+v.z*v.z+v.w*v.w;
            #pragma unroll
            for (int m = 1; m < 64; m <<= 1){
                s += __shfl_xor(s, m, 64); q += __shfl_xor(q, m, 64);
            }
            float mu = s*(1.f/256.f);
            float rs = rsqrtf(q*(1.f/256.f) - mu*mu + 1e-5f);
            float4 o = make_float4((v.x-mu)*rs*gg.x+bb.x, (v.y-mu)*rs*gg.y+bb.y,
                                   (v.z-mu)*rs*gg.z+bb.z, (v.w-mu)*rs*gg.w+bb.w);
            *(float4*)(hh_out + (size_t)(row0+r)*256 + lane*4) = o;
        }
    }
}

// rc = relu(Hn @ Hn^T), tiled GEMM. Grid (63, 4, batches_in_chunk).
__global__ __launch_bounds__(256) void k_corr(const float* __restrict__ HnTc,
                                              float* __restrict__ rcb)
{
    __shared__ float sA[64][32];
    __shared__ float sB[64][128];
    const int tid = threadIdx.x;
    const float* H = HnTc + (size_t)blockIdx.z * 64 * N;
    float* rc = rcb + (size_t)blockIdx.z * N * N;
    const int n0 = blockIdx.x * 32;
    const int cs = blockIdx.y * 512;
    const int ce = (cs + 512 < N) ? cs + 512 : N;
    #pragma unroll
    for (int j = 0; j < 8; ++j){
        int idx = tid + 256*j;
        int k = idx >> 5, r = idx & 31;
        int nn = n0 + r;
        sA[k][r] = (nn < N) ? H[(size_t)k*N + nn] : 0.f;
    }
    const int trow = tid >> 6;
    const int tcol = tid & 63;
    for (int mc = cs; mc < ce; mc += 128){
        __syncthreads();
        #pragma unroll
        for (int q = 0; q < 8; ++q){
            int f = tid + 256*q;
            int k = f >> 5, c4 = (f & 31) * 4;
            int m = mc + c4;
            float4 v = (m + 3 < N) ? *(const float4*)(H + (size_t)k*N + m)
                                   : make_float4(0.f,0.f,0.f,0.f);
            *(float4*)&sB[k][c4] = v;
        }
        __syncthreads();
        float acc[8][2];
        #pragma unroll
        for (int r = 0; r < 8; ++r){ acc[r][0] = 0.f; acc[r][1] = 0.f; }
        #pragma unroll 4
        for (int k = 0; k < 64; ++k){
            float2 b2v = *(const float2*)&sB[k][tcol*2];
            float4 a0 = *(const float4*)&sA[k][trow*8];
            float4 a1 = *(const float4*)&sA[k][trow*8 + 4];
            float av[8] = {a0.x,a0.y,a0.z,a0.w,a1.x,a1.y,a1.z,a1.w};
            #pragma unroll
            for (int r = 0; r < 8; ++r){
                acc[r][0] = fmaf(av[r], b2v.x, acc[r][0]);
                acc[r][1] = fmaf(av[r], b2v.y, acc[r][1]);
            }
        }
        int m = mc + tcol*2;
        if (m < N){
            #pragma unroll
            for (int r = 0; r < 8; ++r){
                int nn = n0 + trow*8 + r;
                if (nn < N){
                    float2 o = make_float2(fmaxf(acc[r][0],0.f), fmaxf(acc[r][1],0.f));
                    *(float2*)(rc + (size_t)nn*N + m) = o;
                }
            }
        }
    }
}

// Per-row selection (softmax + 2x top-20) and sparse aggregation.
// ONE ROW PER WAVE, 4 rows per block. Zn staged in LDS in 8 chunks of 256
// rows as 4 SoA float4 planes in a flat buffer with plane stride 260
// (260 mod 8 == 4 -> both staging writes and plane reads are 2-way bank
// aliased = free). All barriers uniform.
__global__ __launch_bounds__(256) void k_select(
    const float* __restrict__ rcb, const float* __restrict__ Zn,
    const float* __restrict__ hh, const float* __restrict__ mix_logit,
    float* __restrict__ msg, int row_base)
{
    __shared__ float4 zqf[1040];        // 4 planes x 260 slots (256 used)
    __shared__ float cl[4][128];
    __shared__ int   lm[4][64];
    __shared__ float lv[4][64];
    const int tid = threadIdx.x;
    const int lane = tid & 63, wv = tid >> 6;
    const int rloc = blockIdx.x * 4 + wv;   // row within this rc chunk
    const int n = row_base + rloc;          // global row
    const int base = (n / N) * N;
    const float* rcrow = rcb + (size_t)rloc * N;
    float* clw = cl[wv];
    float zr[16];
    {   // own row's Zn (wave-uniform)
        const float4* zp = (const float4*)(Zn + (size_t)n * 16);
        float4 z0 = zp[0], z1 = zp[1], z2 = zp[2], z3 = zp[3];
        zr[0]=z0.x; zr[1]=z0.y; zr[2]=z0.z; zr[3]=z0.w;
        zr[4]=z1.x; zr[5]=z1.y; zr[6]=z1.z; zr[7]=z1.w;
        zr[8]=z2.x; zr[9]=z2.y; zr[10]=z2.z; zr[11]=z2.w;
        zr[12]=z3.x; zr[13]=z3.y; zr[14]=z3.z; zr[15]=z3.w;
    }
    float e_[32], rc_[32];
    float sumE = 0.f, sumC = 0.f;
    #pragma unroll
    for (int c = 0; c < 8; ++c){
        if (c > 0) __syncthreads();     // uniform: previous chunk fully read
        {   // stage 256 Zn rows into 4 planes (cooperative, coalesced)
            #pragma unroll
            for (int k = 0; k < 4; ++k){
                int idx = tid + k*256;          // 0..1023
                int ml = idx >> 2, q = idx & 3;
                int m = c*256 + ml;
                float4 v = make_float4(0.f,0.f,0.f,0.f);
                if (m < N) v = *(const float4*)(Zn + (size_t)(base + m)*16 + q*4);
                zqf[q*260 + ml] = v;
            }
        }
        __syncthreads();                // uniform: staging visible
        #pragma unroll
        for (int j = 0; j < 4; ++j){
            const int i = c*4 + j;
            const int ml = lane + 64*j;
            const int m = c*256 + ml;
            float rcv = -1.f, e = 0.f;
            if (m < N){
                rcv = rcrow[m];
                float4 za = zqf[ml], zb = zqf[260 + ml], zc = zqf[520 + ml], zd = zqf[780 + ml];
                float s = za.x * zr[0];
                s = fmaf(za.y, zr[1], s);  s = fmaf(za.z, zr[2], s);  s = fmaf(za.w, zr[3], s);
                s = fmaf(zb.x, zr[4], s);  s = fmaf(zb.y, zr[5], s);  s = fmaf(zb.z, zr[6], s);
                s = fmaf(zb.w, zr[7], s);  s = fmaf(zc.x, zr[8], s);  s = fmaf(zc.y, zr[9], s);
                s = fmaf(zc.z, zr[10], s); s = fmaf(zc.w, zr[11], s); s = fmaf(zd.x, zr[12], s);
                s = fmaf(zd.y, zr[13], s); s = fmaf(zd.z, zr[14], s); s = fmaf(zd.w, zr[15], s);
                e = __expf(s);          // |s| <= 1, safe without max-subtraction
                sumE += e; sumC += rcv;
            }
            e_[i] = e; rc_[i] = rcv;
        }
    }
    __syncthreads();                    // uniform: zqf no longer needed
    #pragma unroll
    for (int mm = 1; mm < 64; mm <<= 1){
        sumE += __shfl_xor(sumE, mm, 64);
        sumC += __shfl_xor(sumC, mm, 64);
    }
    float c_kth = wave_topk20_sync(rc_, clw);
    float skl = 0.f;
    #pragma unroll
    for (int i = 0; i < 32; ++i){ if (rc_[i] >= c_kth) skl += rc_[i]; }
    #pragma unroll
    for (int mm = 1; mm < 64; mm <<= 1) skl += __shfl_xor(skl, mm, 64);
    const float invSumExp = 1.f / sumE;
    const float r1 = 1.f / (sumC + EPSF);
    const float rollsc = r1 * (1.f / (skl * r1 + EPSF));
    const float mixw = 1.f / (1.f + __expf(-mix_logit[0]));
    const float onemix = 1.f - mixw;
    float sumAm = 0.f;
    #pragma unroll
    for (int i = 0; i < 32; ++i){       // e_ becomes am in place
        float am = -1.f;
        if (rc_[i] >= 0.f){
            float afdg  = e_[i] * invSumExp;
            float aroll = (rc_[i] >= c_kth) ? rc_[i] * rollsc : 0.f;
            am = fmaf(mixw, afdg, onemix * aroll);
            sumAm += am;
        }
        e_[i] = am;
    }
    #pragma unroll
    for (int mm = 1; mm < 64; mm <<= 1) sumAm += __shfl_xor(sumAm, mm, 64);
    float am_kth = wave_topk20_sync(e_, clw);
    float sk2 = 0.f;
    #pragma unroll
    for (int i = 0; i < 32; ++i){ if (e_[i] >= am_kth) sk2 += e_[i]; }
    #pragma unroll
    for (int mm = 1; mm < 64; mm <<= 1) sk2 += __shfl_xor(sk2, mm, 64);
    const float ra = 1.f / (sumAm + EPSF);
    const float fsc = ra * (1.f / (sk2 * ra + EPSF));
    // deterministic compaction of kept entries into this wave's list
    unsigned keep = 0; int cnt = 0;
    #pragma unroll
    for (int i = 0; i < 32; ++i){
        bool kp = (e_[i] >= am_kth) && (e_[i] > 0.f);
        if (kp){ keep |= (1u << i); cnt++; }
    }
    int incl = cnt;
    #pragma unroll
    for (int s = 1; s < 64; s <<= 1){
        int o = __shfl_up(incl, s, 64);
        if (lane >= s) incl += o;
    }
    int total = __shfl(incl, 63, 64);
    if (total > 64) total = 64;
    int offs = incl - cnt;
    #pragma unroll
    for (int i = 0; i < 32; ++i){
        if (keep & (1u << i)){
            if (offs < 64){
                lm[wv][offs] = (i >> 2)*256 + lane + 64*(i & 3);
                lv[wv][offs] = e_[i] * fsc;
            }
            offs++;
        }
    }
    __syncthreads();                    // uniform: fences lm/lv writes
    // msg[n, lane*4 .. +3] = sum_kept w * hh[m, :]
    float a0 = 0.f, a1 = 0.f, a2 = 0.f, a3 = 0.f;
    for (int i = 0; i < total; ++i){
        float w = lv[wv][i];
        const float4 hv = *(const float4*)(hh + ((size_t)(base + lm[wv][i]))*256 + lane*4);
        a0 = fmaf(w, hv.x, a0); a1 = fmaf(w, hv.y, a1);
        a2 = fmaf(w, hv.z, a2); a3 = fmaf(w, hv.w, a3);
    }
    *(float4*)(msg + (size_t)n*256 + lane*4) = make_float4(a0, a1, a2, a3);
}

// Graph-residual MLP + head. MFMA bf16. 16 rows/block, 500 blocks.
__global__ __launch_bounds__(256) void k_gblk(
    const float* __restrict__ hid, const float* __restrict__ msgb,
    const unsigned short* __restrict__ Wtb,
    const float* __restrict__ b1, const float* __restrict__ b2,
    const float* __restrict__ hg, const float* __restrict__ hb,
    const float* __restrict__ hw, const float* __restrict__ hbias,
    float* __restrict__ y)
{
    __shared__ float sR[16][264];
    __shared__ unsigned short sA[16][264];
    const int tid = threadIdx.x;
    const int lane = tid & 63, wave = tid >> 6;
    const int l15 = lane & 15, hi = lane >> 4;
    const int cbase = wave * 64;
    const int row0 = blockIdx.x * 16;
    {   // hid -> sR (f32), msg -> sA (bf16)
        const int r = tid >> 4, cb = (tid & 15) * 4;
        #pragma unroll
        for (int q = 0; q < 4; ++q){
            *(float4*)&sR[r][cb + q*64] =
                *(const float4*)(hid + (size_t)(row0+r)*256 + cb + q*64);
            float4 mv = *(const float4*)(msgb + (size_t)(row0+r)*256 + cb + q*64);
            ushort4 u;
            u.x = f2bf(mv.x); u.y = f2bf(mv.y); u.z = f2bf(mv.z); u.w = f2bf(mv.w);
            *(ushort4*)&sA[r][cb + q*64] = u;
        }
    }
    __syncthreads();
    {   // GEMM1 + gelu -> sA
        f32x4 acc[4];
        #pragma unroll
        for (int t = 0; t < 4; ++t){ acc[t][0]=0.f; acc[t][1]=0.f; acc[t][2]=0.f; acc[t][3]=0.f; }
        mfma_gemm16(sA, Wtb + (size_t)4*65536, l15, hi, cbase, acc);
        #pragma unroll
        for (int t = 0; t < 4; ++t){
            int ct = cbase + t*16 + l15;
            float bbx = b1[ct];
            #pragma unroll
            for (int j = 0; j < 4; ++j)
                sA[hi*4 + j][ct] = f2bf(gelu_t(acc[t][j] + bbx));
        }
    }
    __syncthreads();
    {   // GEMM2 + bias + residual -> sR
        f32x4 acc[4];
        #pragma unroll
        for (int t = 0; t < 4; ++t){ acc[t][0]=0.f; acc[t][1]=0.f; acc[t][2]=0.f; acc[t][3]=0.f; }
        mfma_gemm16(sA, Wtb + (size_t)5*65536, l15, hi, cbase, acc);
        #pragma unroll
        for (int t = 0; t < 4; ++t){
            int ct = cbase + t*16 + l15;
            float bbx = b2[ct];
            #pragma unroll
            for (int j = 0; j < 4; ++j)
                sR[hi*4 + j][ct] += acc[t][j] + bbx;
        }
    }
    __syncthreads();
    {   // head: y = gelu(LN(sR)) @ head_w + head_b; wave owns rows wave*4+j
        float4 gg = *(const float4*)(hg + lane*4);
        float4 bb = *(const float4*)(hb + lane*4);
        float4 wv = *(const float4*)(hw + lane*4);
        #pragma unroll
        for (int j = 0; j < 4; ++j){
            const int r = wave*4 + j;
            float4 v = *(const float4*)&sR[r][lane*4];
            float s = v.x+v.y+v.z+v.w;
            float q = v.x*v.x+v.y*v.y+v.z*v.z+v.w*v.w;
            #pragma unroll
            for (int m = 1; m < 64; m <<= 1){
                s += __shfl_xor(s, m, 64); q += __shfl_xor(q, m, 64);
            }
            float mu = s*(1.f/256.f);
            float rs = rsqrtf(q*(1.f/256.f) - mu*mu + 1e-5f);
            float p = gelu_t((v.x-mu)*rs*gg.x+bb.x)*wv.x
                    + gelu_t((v.y-mu)*rs*gg.y+bb.y)*wv.y
                    + gelu_t((v.z-mu)*rs*gg.z+bb.z)*wv.z
                    + gelu_t((v.w-mu)*rs*gg.w+bb.w)*wv.w;
            #pragma unroll
            for (int m = 1; m < 64; m <<= 1) p += __shfl_xor(p, m, 64);
            if (lane == 0) y[row0 + r] = p + hbias[0];
        }
    }
}

// ---------------- launch ----------------

extern "C" void kernel_launch(void* const* d_in, const int* in_sizes, int n_in,
                              void* d_out, int out_size, void* d_ws, size_t ws_size,
                              hipStream_t stream)
{
    (void)in_sizes; (void)n_in; (void)out_size;
    const float* X         = (const float*)d_in[0];
    const float* history   = (const float*)d_in[2];
    const float* enc_ln_g  = (const float*)d_in[3];
    const float* enc_ln_b  = (const float*)d_in[4];
    const float* enc_w1    = (const float*)d_in[5];
    const float* enc_b1    = (const float*)d_in[6];
    const float* enc_w2    = (const float*)d_in[7];
    const float* enc_b2    = (const float*)d_in[8];
    const float* proj_w    = (const float*)d_in[9];
    const float* proj_b    = (const float*)d_in[10];
    const float* fdg_B     = (const float*)d_in[11];
    const float* mixlog    = (const float*)d_in[12];
    const float* gblk_ln_g = (const float*)d_in[13];
    const float* gblk_ln_b = (const float*)d_in[14];
    const float* gblk_w1   = (const float*)d_in[15];
    const float* gblk_b1   = (const float*)d_in[16];
    const float* gblk_w2   = (const float*)d_in[17];
    const float* gblk_b2   = (const float*)d_in[18];
    const float* head_ln_g = (const float*)d_in[19];
    const float* head_ln_b = (const float*)d_in[20];
    const float* head_w    = (const float*)d_in[21];
    const float* head_b    = (const float*)d_in[22];

    float* ws  = (float*)d_ws;
    float* hid = ws;                              // 2,048,000 f
    float* hh  = hid + (size_t)NROWS*DH;          // 2,048,000 f
    float* msg = hh  + (size_t)NROWS*DH;          // 2,048,000 f
    float* Znb = msg + (size_t)NROWS*DH;          //   128,000 f
    float* HnT = Znb + (size_t)NROWS*16;          //   512,000 f
    unsigned short* Wtb = (unsigned short*)(HnT + (size_t)NB*64*N);  // 6*65536 us
    float* rcbuf = (float*)(Wtb + (size_t)6*65536);
    float* y   = (float*)d_out;

    const size_t baseF = (size_t)3*NROWS*DH + (size_t)NROWS*16 + (size_t)NB*64*N
                       + (size_t)6*65536/2;
    const size_t perBatchF = (size_t)N*N;
    size_t availF = (ws_size/4 > baseF) ? (ws_size/4 - baseF) : perBatchF;
    int bpc = (availF >= 4*perBatchF) ? 4 : (availF >= 2*perBatchF) ? 2 : 1;

    k_wcvt<<<dim3(8,8,6), 256, 0, stream>>>(
        (const float*)d_in[25], (const float*)d_in[27],
        (const float*)d_in[31], (const float*)d_in[33],
        gblk_w1, gblk_w2, Wtb);
    k_enc<<<NROWS/8, 256, 0, stream>>>(X, enc_ln_g, enc_ln_b, enc_w1, enc_b1, enc_w2, enc_b2,
                                       proj_w, proj_b, fdg_B, hid, Znb);
    k_hist<<<NROWS/4, 256, 0, stream>>>(history, HnT);
    k_mlp2<<<NROWS/16, 256, 0, stream>>>(hid, Wtb,
        (const float*)d_in[23], (const float*)d_in[24],
        (const float*)d_in[26], (const float*)d_in[28],
        (const float*)d_in[29], (const float*)d_in[30],
        (const float*)d_in[32], (const float*)d_in[34],
        gblk_ln_g, gblk_ln_b, hh);
    for (int cb = 0; cb < NB; cb += bpc){
        dim3 g1(63, 4, bpc);
        k_corr<<<g1, 256, 0, stream>>>(HnT + (size_t)cb*64*N, rcbuf);
        k_select<<<bpc*N/4, 256, 0, stream>>>(rcbuf, Znb, hh, mixlog, msg, cb*N);
    }
    k_gblk<<<NROWS/16, 256, 0, stream>>>(hid, msg, Wtb, gblk_b1, gblk_b2,
                                         head_ln_g, head_ln_b, head_w, head_b, y);
}